// Round 5
// baseline (559.115 us; speedup 1.0000x reference)
//
#include <hip/hip_runtime.h>
#include <hip/hip_fp16.h>
#include <math.h>

// ---------------------------------------------------------------------------
// Mamba2 stereo SSD block. All GEMM-shaped work on f16 MFMA; fp32 dt/cum/exp.
// B=4, L=8192 (64x128), D_MODEL=256, D_INNER=512, NHEADS=4, HEADDIM=128,
// D_STATE=64, CONV_DIM=640, CHUNK=128, NCHUNK=64.
//
// SSD per-tile formulation (side,b,chunk,head):
//   G = C (128x64) . B^T (64x128)            [MFMA, K=64]
//   M_ij = (i>=j) ? G_ij*exp(cum_i-cum_j)*dt_j : 0 ;  M_ii += D_h
//   Y = M (128x128) . X (128lx128p)          [MFMA, K=128]  (D*x folded in M)
//   states_pn = sum_j X_jp * B_jn * dt_j*exp(cumL-cum_j)   [MFMA, K=128]
// then inter-chunk scan; correction Y += exp(cum_i) * C . hprev^T [MFMA].
// X is produced TRANSPOSED ([channel][Lglobal]) by the in_proj GEMM so MFMA
// operands are K-contiguous; causal conv on x runs along contiguous L.
//
// R1: all k_ssd_a LDS tiles XOR-swizzled in 16B chunks (chunk ^= row&7).
// Bank conflicts 1.36e7 -> 1.57e6, dur 83.5 -> 77.2us. Kept.
// R2 FAILED (reverted): 512-thread blocks didn't raise occupancy.
// R3: hot-path expf -> __expf: ssd_a 77->68us, total -24us.
// R4: GEMM XCD-chunked swizzle + small-dim-fastest; k_cum wave-parallel scan.
// Total 544.5 -> 504.8us.
// R5: (a) k_ssd_c + k_rmsnorm fused into k_ssd_cn (per side,b,chunk,half-64-
// rows): stage y rows into swizzled LDS, 4 heads of C.hprev^T MFMA RMW in
// LDS, gate with silu(z), in-wave rmsnorm, single final write. Saves a full
// ybuf write+read (~134MB) and kills the scattered global f16 RMW.
// (b) k_scan: 64 dependent global load->store round-trips -> load-all-64
// into regs (independent, pipelined), scan, store.
//
// Workspace (bytes), total 264,046,592 (~252 MiB):
//   F16    f16 [65536,256]    [0,          33,554,432)
//   ipw16  f16 [1156,256]     [33,554,432, 34,146,304)
//   opw16  f16 [256,512]      [34,146,304, 34,408,448)
//   dtbuf  f32 [8,4,8192]     [34,408,448, 35,457,024)
//   cumbuf f32 [8,4,8192]     [35,457,024, 36,505,600)
//   wbuf   f32 [8,4,8192]     [36,505,600, 37,554,176)
//   xT     f16 [512,65536]    [37,554,176, 104,663,040)  live: gemm -> ssd_a
//   XCt    f16 [512,32768]    [104,663,040,138,217,472)  live: conv -> ssd_a
//   bcLr   f16 [32768,128]    [138,217,472,146,606,080)  raw left B/C
//   bcR    f16 [32768,128]    [146,606,080,154,994,688)  raw right B/C
//   bcL    f16 [32768,128]    [154,994,688,163,383,296)  conv'd left B/C
//   ybuf   f16 [65536,512]    [163,383,296,230,492,160)
//   states f16 [8,64,4,128,64][230,492,160,264,046,592)
//   zbuf   f16 [65536,512]    alias over dead xT
// ---------------------------------------------------------------------------

typedef _Float16 f16;
typedef __attribute__((ext_vector_type(8))) _Float16 f16x8;
typedef __attribute__((ext_vector_type(4))) _Float16 f16x4;
typedef __attribute__((ext_vector_type(4))) float f32x4;

__device__ __forceinline__ float fexpf(float v) { return __expf(v); }
__device__ __forceinline__ float siluf(float v) { return v / (1.0f + __expf(-v)); }

__device__ __forceinline__ void gload_lds16(const void* g, void* l) {
    __builtin_amdgcn_global_load_lds(
        (const __attribute__((address_space(1))) void*)g,
        (__attribute__((address_space(3))) void*)l, 16, 0, 0);
}

// ---------------- fp32 -> f16 cast ------------------------------------------
__global__ __launch_bounds__(256) void k_cvt(
    const float* __restrict__ s, f16* __restrict__ d, int n)
{
    int i = blockIdx.x * 256 + threadIdx.x;
    if (i < n) d[i] = (f16)s[i];
}

// ---------------- downsample: 4x4/4 conv, 3->256 ch, NCHW -> (row, c) f16 ---
__global__ __launch_bounds__(256) void k_downsample(
    const float* __restrict__ limg, const float* __restrict__ rimg,
    const float* __restrict__ w, const float* __restrict__ bias,
    f16* __restrict__ F)
{
    __shared__ float wS[12288];   // [c][48]
    __shared__ float pS[768];     // [pix][48]
    int t = threadIdx.x;
    int bid = blockIdx.x;               // og(8) | oy(64) | b(4) | side(2)
    int og = bid & 7;
    int oy = (bid >> 3) & 63;
    int b  = (bid >> 9) & 3;
    int side = bid >> 11;
    const float* img = side ? rimg : limg;

    for (int e = t * 4; e < 12288; e += 1024)
        *(float4*)(wS + e) = *(const float4*)(w + e);

    int ox0 = og * 16;
    for (int f = t; f < 768; f += 256) {
        int kx = f & 3, pix = (f >> 2) & 15, ky = (f >> 6) & 3, ci = f >> 8;
        float v = img[((b * 3 + ci) * 256 + oy * 4 + ky) * 512 + ox0 * 4 + pix * 4 + kx];
        pS[pix * 48 + ci * 16 + ky * 4 + kx] = v;
    }
    __syncthreads();

    int c = t;
    float wreg[48];
#pragma unroll
    for (int q = 0; q < 12; q++) {
        float4 v = *(const float4*)(wS + c * 48 + q * 4);
        wreg[q * 4 + 0] = v.x; wreg[q * 4 + 1] = v.y;
        wreg[q * 4 + 2] = v.z; wreg[q * 4 + 3] = v.w;
    }
    float bv = bias[c];
    long base = ((long)(side * 32768 + b * 8192 + oy * 128 + ox0)) * 256 + c;
    for (int pix = 0; pix < 16; pix++) {
        float acc = bv;
#pragma unroll
        for (int q = 0; q < 12; q++) {
            float4 p4 = *(const float4*)(pS + pix * 48 + q * 4);
            acc += wreg[q * 4 + 0] * p4.x + wreg[q * 4 + 1] * p4.y
                 + wreg[q * 4 + 2] * p4.z + wreg[q * 4 + 3] * p4.w;
        }
        F[base + (long)pix * 256] = (f16)acc;
    }
}

// ---------------- f16 MFMA NT GEMM: C[m,n] = sum_k A[m,k]*B[n,k] ------------
// 128x128 tile, BK=64, 4 waves (2x2), each wave 4x4 frags of 16x16x32.
// lda = ldb = K. Output rows >= split go to CR (row-split).
// Grid is (m_tiles, n_tiles); requires (m_tiles*n_tiles) % 8 == 0.
// R4: XCD-chunked bijective swizzle + small-tile-dim-fastest enumeration so
// consecutive blocks on one XCD reuse the large operand tile in its L2.
template<typename TO>
__global__ __launch_bounds__(256) void k_gemm_mfma(
    const f16* __restrict__ A, const f16* __restrict__ B,
    TO* __restrict__ CL, TO* __restrict__ CR, int K, int ldc, int split)
{
    __shared__ f16 As[128 * 64];
    __shared__ f16 Bs[128 * 64];
    int t = threadIdx.x;
    int w = t >> 6, lane = t & 63;
    int wm = w >> 1, wn = w & 1;

    int gx = gridDim.x, gy = gridDim.y;          // (m_tiles, n_tiles)
    int nwg = gx * gy;
    int orig = blockIdx.y * gx + blockIdx.x;     // dispatch order (x fastest)
    int swz = (orig & 7) * (nwg >> 3) + (orig >> 3);   // chunked XCD swizzle
    int mt, nt;
    if (gx <= gy) { mt = swz % gx; nt = swz / gx; }    // share B-tile
    else          { nt = swz % gy; mt = swz / gy; }    // share A-tile
    long m0 = (long)mt * 128;
    int n0 = nt * 128;

    f32x4 acc[4][4] = {};

    const f16* ga = A + (m0 + w * 8 + (lane >> 3)) * K + (lane & 7) * 8;
    const f16* gb = B + ((long)n0 + w * 8 + (lane >> 3)) * K + (lane & 7) * 8;
    f16* la = As + (w * 8) * 64;
    f16* lb = Bs + (w * 8) * 64;

    for (int kk = 0; kk < K; kk += 64) {
#pragma unroll
        for (int i = 0; i < 4; i++) {
            gload_lds16(ga + (long)i * 32 * K + kk, la + i * 32 * 64);
            gload_lds16(gb + (long)i * 32 * K + kk, lb + i * 32 * 64);
        }
        __syncthreads();

        const f16* pa = As + (wm * 64 + (lane & 15)) * 64 + (lane >> 4) * 8;
        const f16* pb = Bs + (wn * 64 + (lane & 15)) * 64 + (lane >> 4) * 8;
#pragma unroll
        for (int kb = 0; kb < 2; kb++) {
            f16x8 af[4], bf[4];
#pragma unroll
            for (int r = 0; r < 4; r++)
                af[r] = *(const f16x8*)(pa + r * 16 * 64 + kb * 32);
#pragma unroll
            for (int cn = 0; cn < 4; cn++)
                bf[cn] = *(const f16x8*)(pb + cn * 16 * 64 + kb * 32);
#pragma unroll
            for (int r = 0; r < 4; r++)
#pragma unroll
                for (int cn = 0; cn < 4; cn++)
                    acc[r][cn] = __builtin_amdgcn_mfma_f32_16x16x32_f16(
                        af[r], bf[cn], acc[r][cn], 0, 0, 0);
        }
        __syncthreads();
    }

    int rb = (lane >> 4) * 4;
    int cb = lane & 15;
#pragma unroll
    for (int r = 0; r < 4; r++) {
        long mrow = m0 + wm * 64 + r * 16 + rb;
#pragma unroll
        for (int reg = 0; reg < 4; reg++) {
            long row = mrow + reg;
            TO* Cp = (row < split) ? CL + row * ldc : CR + (row - split) * ldc;
#pragma unroll
            for (int cn = 0; cn < 4; cn++)
                Cp[n0 + wn * 64 + cn * 16 + cb] = (TO)acc[r][cn][reg];
        }
    }
}

// ---------------- dt: fp32 dot of F16 row with W rows 1152..1155, softplus --
__global__ __launch_bounds__(256) void k_dt(
    const f16* __restrict__ F, const float* __restrict__ W,
    const float* __restrict__ dt_bias, float* __restrict__ dtbuf)
{
    int t = threadIdx.x;
    int wv = t >> 6, lane = t & 63;
    long m = (long)blockIdx.x * 4 + wv;     // 0..65535
    f16x4 fv = *(const f16x4*)(F + m * 256 + lane * 4);
    float dots[4];
#pragma unroll
    for (int h = 0; h < 4; h++) {
        float4 w4 = *(const float4*)(W + (long)(1152 + h) * 256 + lane * 4);
        float d = (float)fv[0] * w4.x + (float)fv[1] * w4.y
                + (float)fv[2] * w4.z + (float)fv[3] * w4.w;
#pragma unroll
        for (int off = 32; off; off >>= 1) d += __shfl_down(d, off, 64);
        dots[h] = d;
    }
    if (lane == 0) {
        long sb = m >> 13;                  // side*4 + b
        long l = m & 8191;
#pragma unroll
        for (int h = 0; h < 4; h++) {
            float v = dots[h] + dt_bias[h];
            float sp = (v > 20.0f) ? v : log1pf(expf(v));
            dtbuf[(sb * 4 + h) * 8192 + l] = sp;
        }
    }
}

// ---------------- per-chunk cumsum of dt*A, and w = dt*exp(cumL-cum) --------
// R4: wave-parallel. One wave per (sb,h,c) group of 128 elements; lane holds
// 2 elems (float2), 6-step shuffle inclusive scan, fused w computation.
__global__ __launch_bounds__(256) void k_cum(
    const float* __restrict__ dtbuf, const float* __restrict__ A_log,
    float* __restrict__ cumbuf, float* __restrict__ wbuf)
{
    int wv = threadIdx.x >> 6, lane = threadIdx.x & 63;
    int g = blockIdx.x * 4 + wv;                // 2048 = sb(8)*h(4)*c(64)
    int c = g & 63, h = (g >> 6) & 3, sb = g >> 8;
    float A = -__expf(A_log[h]);
    long base = ((long)sb * 4 + h) * 8192 + c * 128;
    float2 d = *(const float2*)(dtbuf + base + lane * 2);
    float a0 = d.x * A;
    float p = a0 + d.y * A;                     // in-lane pair sum
    float s = p;
#pragma unroll
    for (int off = 1; off < 64; off <<= 1) {
        float v = __shfl_up(s, off, 64);
        if (lane >= off) s += v;
    }
    float excl = s - p;
    float c0 = excl + a0, c1 = excl + p;
    float cl = __shfl(s, 63, 64);               // chunk total
    *(float2*)(cumbuf + base + lane * 2) = make_float2(c0, c1);
    *(float2*)(wbuf + base + lane * 2) =
        make_float2(d.x * __expf(cl - c0), d.y * __expf(cl - c1));
}

// ---------------- causal conv1d on transposed x (contiguous along L) --------
__global__ __launch_bounds__(256) void k_conv_x(
    const f16* __restrict__ xT, const float* __restrict__ cw,
    const float* __restrict__ cb, f16* __restrict__ XCt)
{
    int bid = blockIdx.x;               // c(512) | b(4) | tile(4)
    int c = bid >> 4;
    int b = (bid >> 2) & 3;
    int tile = bid & 3;
    int l0 = tile * 2048 + threadIdx.x * 8;
    const f16* row = xT + (long)c * 65536 + b * 8192;   // left cols only
    float w0 = cw[c * 4 + 0], w1 = cw[c * 4 + 1],
          w2 = cw[c * 4 + 2], w3 = cw[c * 4 + 3];
    float bv = cb[c];
    float xv[11];
    f16x8 v = *(const f16x8*)(row + l0);
#pragma unroll
    for (int q = 0; q < 8; q++) xv[3 + q] = (float)v[q];
    if (l0 > 0) {
        xv[0] = (float)row[l0 - 3];
        xv[1] = (float)row[l0 - 2];
        xv[2] = (float)row[l0 - 1];
    } else { xv[0] = xv[1] = xv[2] = 0.f; }
    f16x8 o;
#pragma unroll
    for (int q = 0; q < 8; q++) {
        float acc = bv + w0 * xv[q] + w1 * xv[q + 1] + w2 * xv[q + 2] + w3 * xv[q + 3];
        o[q] = (f16)siluf(acc);
    }
    *(f16x8*)(XCt + (long)c * 32768 + b * 8192 + l0) = o;
}

// ---------------- causal conv1d on left B/C (row-major [l][128]) ------------
__global__ __launch_bounds__(256) void k_conv_bc(
    const f16* __restrict__ bcLr, const float* __restrict__ cw,
    const float* __restrict__ cb, f16* __restrict__ bcL)
{
    long idx = (long)blockIdx.x * 256 + threadIdx.x;    // 32768*128
    int n = (int)(idx & 127);
    long m = idx >> 7;
    int l = (int)(m & 8191);
    float acc = cb[512 + n];
#pragma unroll
    for (int k = 0; k < 4; k++) {
        int j = l - 3 + k;
        if (j >= 0) acc += cw[(512 + n) * 4 + k] * (float)bcLr[(m - 3 + k) * 128 + n];
    }
    bcL[m * 128 + n] = (f16)siluf(acc);
}

// ---------------- SSD phase A: MFMA chunked formulation ---------------------
// LDS 64 KB: Xs[p=128][j=128] (32KB) | Cs[i=128][n=64] (16KB) | Bs[j=128][n=64]
// (16KB); Ms[i=128][j=128] overlays Cs+Bs after G.
// All tiles XOR-swizzled in 16B chunks: phys_chunk = log_chunk ^ (row & 7).
// global_load_lds writes linearly -> inverse swizzle applied to the per-lane
// GLOBAL source column; ds_read fragments and Ms write/read apply the XOR.
__global__ __launch_bounds__(256) void k_ssd_a(
    const f16* __restrict__ xT, const f16* __restrict__ XCt,
    const f16* __restrict__ bcR, const f16* __restrict__ bcL,
    const float* __restrict__ dtbuf, const float* __restrict__ cumbuf,
    const float* __restrict__ wbuf, const float* __restrict__ Dvec,
    f16* __restrict__ ybuf, f16* __restrict__ states)
{
    extern __shared__ f16 sm[];
    f16* Xs = sm;            // [p][j]  swizzled
    f16* Cs = sm + 16384;    // [i][n]  swizzled
    f16* Bs = sm + 24576;    // [j][n]  swizzled
    f16* Ms = sm + 16384;    // [i][j]  overlay, swizzled

    int t = threadIdx.x;
    int w = t >> 6, lane = t & 63;
    int quad = lane >> 4, l16 = lane & 15;
    int wm = w >> 1, wn = w & 1;
    int bid = blockIdx.x;
    int side = bid >> 10, rem = bid & 1023;
    int b = rem >> 8, c = (rem >> 2) & 63, h = rem & 3;
    long l0 = (long)b * 8192 + c * 128;
    long dtbase = ((long)(side * 4 + b) * 4 + h) * 8192 + c * 128;

    const f16* Xg; long ldx;
    const f16 *Bg, *Cg;
    if (side == 0) {
        Xg = xT + (long)(h * 128) * 65536 + 32768 + l0; ldx = 65536;
        Bg = bcR + l0 * 128;
        Cg = bcL + l0 * 128 + 64;
    } else {
        Xg = XCt + (long)(h * 128) * 32768 + l0;        ldx = 32768;
        Bg = bcL + l0 * 128;
        Cg = bcR + l0 * 128 + 64;
    }

    int sw8 = l16 & 7;   // row&7 for all MFMA-phase fragment rows (row%16==l16)

    // stage X (4 rows/call): lane (quad,l16) lands at LDS (row r0+quad, chunk
    // l16) -> source column chunk = l16 ^ (row&7)
#pragma unroll
    for (int q = 0; q < 8; q++) {
        int r0 = w * 32 + q * 4;
        int R = r0 + quad;
        gload_lds16(Xg + (long)R * ldx + ((l16 ^ (R & 7)) << 3), Xs + r0 * 128);
    }
    // stage C and B (8 rows/call): lane lands at (row r0+(lane>>3), chunk
    // lane&7) -> source chunk = (lane&7) ^ (row&7)
#pragma unroll
    for (int q = 0; q < 4; q++) {
        int r0 = w * 32 + q * 8;
        int R = r0 + (lane >> 3);
        int cc = ((lane & 7) ^ (R & 7)) << 3;
        gload_lds16(Cg + (long)R * 128 + cc, Cs + r0 * 64);
        gload_lds16(Bg + (long)R * 128 + cc, Bs + r0 * 64);
    }

    float cum_i[16], cum_j[4], dt_j[4];
#pragma unroll
    for (int r = 0; r < 4; r++)
#pragma unroll
        for (int reg = 0; reg < 4; reg++)
            cum_i[r * 4 + reg] = cumbuf[dtbase + wm * 64 + r * 16 + quad * 4 + reg];
#pragma unroll
    for (int cn = 0; cn < 4; cn++) {
        int j = wn * 64 + cn * 16 + l16;
        cum_j[cn] = cumbuf[dtbase + j];
        dt_j[cn] = dtbuf[dtbase + j];
    }
    float Dh = Dvec[h];
    __syncthreads();

    // G = C . B^T  (K=64)
    f32x4 g[4][4] = {};
#pragma unroll
    for (int kb = 0; kb < 2; kb++) {
        f16x8 af[4], bf[4];
#pragma unroll
        for (int r = 0; r < 4; r++)
            af[r] = *(const f16x8*)(Cs + (wm * 64 + r * 16 + l16) * 64
                                       + (((quad + kb * 4) ^ sw8) << 3));
#pragma unroll
        for (int cn = 0; cn < 4; cn++)
            bf[cn] = *(const f16x8*)(Bs + (wn * 64 + cn * 16 + l16) * 64
                                        + (((quad + kb * 4) ^ sw8) << 3));
#pragma unroll
        for (int r = 0; r < 4; r++)
#pragma unroll
            for (int cn = 0; cn < 4; cn++)
                g[r][cn] = __builtin_amdgcn_mfma_f32_16x16x32_f16(
                    af[r], bf[cn], g[r][cn], 0, 0, 0);
    }
    __syncthreads();

    // M = mask(G)*exp*dt (+D on diagonal), write f16 to LDS (overlay Cs/Bs)
#pragma unroll
    for (int r = 0; r < 4; r++)
#pragma unroll
        for (int cn = 0; cn < 4; cn++)
#pragma unroll
            for (int reg = 0; reg < 4; reg++) {
                int i = wm * 64 + r * 16 + quad * 4 + reg;
                int j = wn * 64 + cn * 16 + l16;
                float v = 0.f;
                if (i >= j)
                    v = g[r][cn][reg] * fexpf(cum_i[r * 4 + reg] - cum_j[cn]) * dt_j[cn];
                if (i == j) v += Dh;
                Ms[i * 128 + ((((j >> 3) ^ (i & 7))) << 3) + (j & 7)] = (f16)v;
            }
    __syncthreads();

    // Y = M . X   (K=128): A=Ms[i][j], B=Xs[p][j]
    f32x4 y[4][4] = {};
#pragma unroll
    for (int kb = 0; kb < 4; kb++) {
        f16x8 af[4], bf[4];
#pragma unroll
        for (int r = 0; r < 4; r++)
            af[r] = *(const f16x8*)(Ms + (wm * 64 + r * 16 + l16) * 128
                                       + (((quad + kb * 4) ^ sw8) << 3));
#pragma unroll
        for (int cn = 0; cn < 4; cn++)
            bf[cn] = *(const f16x8*)(Xs + (wn * 64 + cn * 16 + l16) * 128
                                        + (((quad + kb * 4) ^ sw8) << 3));
#pragma unroll
        for (int r = 0; r < 4; r++)
#pragma unroll
            for (int cn = 0; cn < 4; cn++)
                y[r][cn] = __builtin_amdgcn_mfma_f32_16x16x32_f16(
                    af[r], bf[cn], y[r][cn], 0, 0, 0);
    }
    long ybase = (long)side * 32768 + l0;
#pragma unroll
    for (int r = 0; r < 4; r++)
#pragma unroll
        for (int reg = 0; reg < 4; reg++) {
            int i = wm * 64 + r * 16 + quad * 4 + reg;
#pragma unroll
            for (int cn = 0; cn < 4; cn++) {
                int p = wn * 64 + cn * 16 + l16;
                ybuf[(ybase + i) * 512 + h * 128 + p] = (f16)y[r][cn][reg];
            }
        }

    // states = X^T(weighted B): A=Xs[p][j], B-frags built from global B * w_j
    f32x4 s[4][2] = {};
#pragma unroll
    for (int kb = 0; kb < 4; kb++) {
        float wj[8];
#pragma unroll
        for (int jj = 0; jj < 8; jj++)
            wj[jj] = wbuf[dtbase + kb * 32 + quad * 8 + jj];
        f16x8 af[4], bf[2];
#pragma unroll
        for (int r = 0; r < 4; r++)
            af[r] = *(const f16x8*)(Xs + (wm * 64 + r * 16 + l16) * 128
                                       + (((quad + kb * 4) ^ sw8) << 3));
#pragma unroll
        for (int cn = 0; cn < 2; cn++) {
            int n = wn * 32 + cn * 16 + l16;
#pragma unroll
            for (int jj = 0; jj < 8; jj++) {
                int j = kb * 32 + quad * 8 + jj;
                bf[cn][jj] = (f16)((float)Bg[(long)j * 128 + n] * wj[jj]);
            }
        }
#pragma unroll
        for (int r = 0; r < 4; r++)
#pragma unroll
            for (int cn = 0; cn < 2; cn++)
                s[r][cn] = __builtin_amdgcn_mfma_f32_16x16x32_f16(
                    af[r], bf[cn], s[r][cn], 0, 0, 0);
    }
    long sbase = (((long)(side * 4 + b) * 64 + c) * 4 + h) * 128;
#pragma unroll
    for (int r = 0; r < 4; r++)
#pragma unroll
        for (int reg = 0; reg < 4; reg++) {
            int p = wm * 64 + r * 16 + quad * 4 + reg;
#pragma unroll
            for (int cn = 0; cn < 2; cn++) {
                int n = wn * 32 + cn * 16 + l16;
                states[(sbase + p) * 64 + n] = (f16)s[r][cn][reg];
            }
        }
}

// ---------------- inter-chunk scan over 64 chunks (in place, fp16) ----------
// R5: load all 64 chunk-values into regs first (independent loads pipeline
// under vmcnt) instead of a 64-deep dependent load->store chain.
__global__ __launch_bounds__(256) void k_scan(
    f16* __restrict__ states, const float* __restrict__ cumbuf)
{
    long g = (long)blockIdx.x * 256 + threadIdx.x;   // 262144 threads
    int n = (int)(g & 63);
    int p = (int)((g >> 6) & 127);
    int h = (int)((g >> 13) & 3);
    int sb = (int)(g >> 15);                         // side*4+b
    long sbase = (((long)sb * 256 + h) * 128 + p) * 64 + n;   // c=0
    long cbase = ((long)sb * 4 + h) * 8192 + 127;
    float sv[64];
#pragma unroll
    for (int c = 0; c < 64; c++)
        sv[c] = (float)states[sbase + (long)c * 32768];
    float hr = 0.f;
#pragma unroll
    for (int c = 0; c < 64; c++) {
        states[sbase + (long)c * 32768] = (f16)hr;   // hprev for chunk c
        hr = hr * fexpf(cumbuf[cbase + (long)c * 128]) + sv[c];
    }
}

// ---------------- fused SSD phase C + gated rmsnorm -------------------------
// Per block: (side,b,chunk,half) = 64 rows x 512 cols. 256 threads, 4 waves.
// LDS 64KB: gS f16 [64][512], 16B-chunk XOR-swizzled (chunk ^= (row&7)<<3).
// P0: stage y rows coalesced -> gS.
// P1: for h in 0..3: corr = C(64x64) . hprev^T(128x64) [MFMA, wave grid 2x2,
//     acc 2x4]; gS[i][h*128+p] += exp(cum_i)*corr (scalar LDS RMW).
// P2: row-linear: g = gS * silu(z); ssq shfl-reduce over 4 threads/row;
//     out = g * rsqrt(mean+eps) * nw -> ybuf. One ybuf write total.
__global__ __launch_bounds__(256) void k_ssd_cn(
    const f16* __restrict__ bcR, const f16* __restrict__ bcL,
    const f16* __restrict__ states, const float* __restrict__ cumbuf,
    const f16* __restrict__ zbuf, const float* __restrict__ nw,
    f16* __restrict__ ybuf)
{
    extern __shared__ f16 gS[];   // [64][512] swizzled
    int t = threadIdx.x;
    int w = t >> 6, lane = t & 63;
    int quad = lane >> 4, l16 = lane & 15;
    int wm = w >> 1, wn = w & 1;
    int bid = blockIdx.x;                 // sb(8) | c(64) | half(2)
    int sb = bid >> 7, c = (bid >> 1) & 63, half = bid & 1;
    int side = sb >> 2, b = sb & 3;
    long lrow0 = (long)b * 8192 + c * 128 + half * 64;   // row in per-side bufs
    long grow0 = (long)side * 32768 + lrow0;             // row in ybuf/zbuf

    // ---- P0: stage y -> gS (coalesced, swizzled) ----
    {
        int row = t >> 2, quarter = t & 3;
        const f16* src = ybuf + (grow0 + row) * 512 + quarter * 128;
        f16* dst = gS + row * 512;
        int sw = (row & 7) << 3;
#pragma unroll
        for (int k = 0; k < 16; k++) {
            int lg = quarter * 16 + k;
            *(f16x8*)(dst + ((lg ^ sw) << 3)) = *(const f16x8*)(src + k * 8);
        }
    }
    __syncthreads();

    // ---- P1: per-head correction MFMA, RMW into gS ----
    const f16* Cg = ((side == 0) ? bcL : bcR) + lrow0 * 128 + 64;
    f16x8 af[2][2];
#pragma unroll
    for (int r = 0; r < 2; r++)
#pragma unroll
        for (int kb = 0; kb < 2; kb++)
            af[r][kb] = *(const f16x8*)(Cg + (long)(wm * 32 + r * 16 + l16) * 128
                                           + quad * 8 + kb * 32);
#pragma unroll
    for (int h = 0; h < 4; h++) {
        long stile = (((long)sb * 64 + c) * 4 + h) * 8192;
        f32x4 acc[2][4] = {};
#pragma unroll
        for (int kb = 0; kb < 2; kb++) {
            f16x8 bf[4];
#pragma unroll
            for (int cn = 0; cn < 4; cn++)
                bf[cn] = *(const f16x8*)(states + stile
                            + (long)(wn * 64 + cn * 16 + l16) * 64 + quad * 8 + kb * 32);
#pragma unroll
            for (int r = 0; r < 2; r++)
#pragma unroll
                for (int cn = 0; cn < 4; cn++)
                    acc[r][cn] = __builtin_amdgcn_mfma_f32_16x16x32_f16(
                        af[r][kb], bf[cn], acc[r][cn], 0, 0, 0);
        }
        long dtb = ((long)sb * 4 + h) * 8192 + c * 128 + half * 64;
#pragma unroll
        for (int r = 0; r < 2; r++)
#pragma unroll
            for (int reg = 0; reg < 4; reg++) {
                int i = wm * 32 + r * 16 + quad * 4 + reg;
                float ex = fexpf(cumbuf[dtb + i]);
                int sw = (i & 7) << 3;
#pragma unroll
                for (int cn = 0; cn < 4; cn++) {
                    int col = h * 128 + wn * 64 + cn * 16 + l16;
                    int addr = i * 512 + ((((col >> 3) ^ sw)) << 3) + (col & 7);
                    gS[addr] = (f16)((float)gS[addr] + ex * acc[r][cn][reg]);
                }
            }
    }
    __syncthreads();

    // ---- P2: gate with silu(z), rmsnorm, write ybuf ----
    {
        int row = t >> 2, quarter = t & 3;
        int sw = (row & 7) << 3;
        long grow = grow0 + row;
        const f16* zrow = zbuf + grow * 512 + quarter * 128;
        f16x8 gv[16];
        float ssq = 0.f;
#pragma unroll
        for (int k = 0; k < 16; k++) {
            int lg = quarter * 16 + k;
            f16x8 yv = *(const f16x8*)(gS + row * 512 + ((lg ^ sw) << 3));
            f16x8 zv = *(const f16x8*)(zrow + k * 8);
            f16x8 gg;
#pragma unroll
            for (int q = 0; q < 8; q++) {
                float gf = (float)yv[q] * siluf((float)zv[q]);
                gg[q] = (f16)gf;
                ssq += gf * gf;
            }
            gv[k] = gg;
        }
        ssq += __shfl_xor(ssq, 1, 64);
        ssq += __shfl_xor(ssq, 2, 64);
        float sc = rsqrtf(ssq * (1.0f / 512.0f) + 1e-5f);
        f16* orow = ybuf + grow * 512 + quarter * 128;
#pragma unroll
        for (int k = 0; k < 16; k++) {
            float4 w0 = *(const float4*)(nw + quarter * 128 + k * 8);
            float4 w1 = *(const float4*)(nw + quarter * 128 + k * 8 + 4);
            f16x8 o;
            o[0] = (f16)((float)gv[k][0] * sc * w0.x);
            o[1] = (f16)((float)gv[k][1] * sc * w0.y);
            o[2] = (f16)((float)gv[k][2] * sc * w0.z);
            o[3] = (f16)((float)gv[k][3] * sc * w0.w);
            o[4] = (f16)((float)gv[k][4] * sc * w1.x);
            o[5] = (f16)((float)gv[k][5] * sc * w1.y);
            o[6] = (f16)((float)gv[k][6] * sc * w1.z);
            o[7] = (f16)((float)gv[k][7] * sc * w1.w);
            *(f16x8*)(orow + k * 8) = o;
        }
    }
}

// ---------------------------------------------------------------------------
extern "C" void kernel_launch(void* const* d_in, const int* in_sizes, int n_in,
                              void* d_out, int out_size, void* d_ws, size_t ws_size,
                              hipStream_t stream)
{
    (void)in_sizes; (void)n_in; (void)out_size; (void)ws_size;
    const float* limg = (const float*)d_in[0];
    const float* rimg = (const float*)d_in[1];
    const float* dsw  = (const float*)d_in[2];
    const float* dsb  = (const float*)d_in[3];
    const float* ipw  = (const float*)d_in[4];
    const float* cw   = (const float*)d_in[5];
    const float* cb   = (const float*)d_in[6];
    const float* dtb  = (const float*)d_in[7];
    const float* alog = (const float*)d_in[8];
    const float* Dv   = (const float*)d_in[9];
    const float* nw   = (const float*)d_in[10];
    const float* opw  = (const float*)d_in[11];
    float* out = (float*)d_out;

    char* ws = (char*)d_ws;
    f16*   F16    = (f16*)  (ws + 0);
    f16*   ipw16  = (f16*)  (ws + 33554432);
    f16*   opw16  = (f16*)  (ws + 34146304);
    float* dtbuf  = (float*)(ws + 34408448);
    float* cumbuf = (float*)(ws + 35457024);
    float* wbuf   = (float*)(ws + 36505600);
    f16*   xT     = (f16*)  (ws + 37554176);
    f16*   XCt    = (f16*)  (ws + 104663040);
    f16*   bcLr   = (f16*)  (ws + 138217472);
    f16*   bcR    = (f16*)  (ws + 146606080);
    f16*   bcL    = (f16*)  (ws + 154994688);
    f16*   ybuf   = (f16*)  (ws + 163383296);
    f16*   states = (f16*)  (ws + 230492160);
    f16*   zbuf   = xT;                          // alias (xT dead after ssd_a)

    const int BIG = 1 << 30;
    k_downsample<<<4096, 256, 0, stream>>>(limg, rimg, dsw, dsb, F16);
    k_cvt<<<1156, 256, 0, stream>>>(ipw, ipw16, 1156 * 256);
    k_cvt<<<512, 256, 0, stream>>>(opw, opw16, 256 * 512);
    // B/C columns (weights rows 1024..1151): out [l][128], split L/R
    k_gemm_mfma<f16><<<dim3(512, 1), 256, 0, stream>>>(
        F16, ipw16 + 1024 * 256, bcLr, bcR, 256, 128, 32768);
    // x columns TRANSPOSED: A=weights rows 512..1023, B=F16 -> xT[512][65536]
    k_gemm_mfma<f16><<<dim3(4, 512), 256, 0, stream>>>(
        ipw16 + 512 * 256, F16, xT, xT, 256, 65536, BIG);
    k_dt<<<16384, 256, 0, stream>>>(F16, ipw, dtb, dtbuf);
    k_cum<<<512, 256, 0, stream>>>(dtbuf, alog, cumbuf, wbuf);
    k_conv_x<<<8192, 256, 0, stream>>>(xT, cw, cb, XCt);
    k_conv_bc<<<16384, 256, 0, stream>>>(bcLr, cw, cb, bcL);
    k_ssd_a<<<2048, 256, 65536, stream>>>(
        xT, XCt, bcR, bcL, dtbuf, cumbuf, wbuf, Dv, ybuf, states);
    k_scan<<<1024, 256, 0, stream>>>(states, cumbuf);
    // z = F @ ipw[0:512]^T (into region freed by xT) -- before fused epilogue
    k_gemm_mfma<f16><<<dim3(512, 4), 256, 0, stream>>>(
        F16, ipw16, zbuf, zbuf, 256, 512, BIG);
    // fused: y += exp(cum)*C.hprev^T ; y = rmsnorm(y*silu(z))*nw
    k_ssd_cn<<<1024, 256, 65536, stream>>>(
        bcR, bcL, states, cumbuf, zbuf, nw, ybuf);
    // out = y @ opw^T (fp32 out), split L/R halves of d_out
    k_gemm_mfma<float><<<dim3(512, 2), 256, 0, stream>>>(
        ybuf, opw16, out, out + (long)32768 * 256, 512, 256, 32768);
}

// Round 6
// 508.570 us; speedup vs baseline: 1.0994x; 1.0994x over previous
//
#include <hip/hip_runtime.h>
#include <hip/hip_fp16.h>
#include <math.h>

// ---------------------------------------------------------------------------
// Mamba2 stereo SSD block. All GEMM-shaped work on f16 MFMA; fp32 dt/cum/exp.
// B=4, L=8192 (64x128), D_MODEL=256, D_INNER=512, NHEADS=4, HEADDIM=128,
// D_STATE=64, CONV_DIM=640, CHUNK=128, NCHUNK=64.
//
// SSD per-tile formulation (side,b,chunk,head):
//   G = C (128x64) . B^T (64x128)            [MFMA, K=64]
//   M_ij = (i>=j) ? G_ij*exp(cum_i-cum_j)*dt_j : 0 ;  M_ii += D_h
//   Y = M (128x128) . X (128lx128p)          [MFMA, K=128]  (D*x folded in M)
//   states_pn = sum_j X_jp * B_jn * dt_j*exp(cumL-cum_j)   [MFMA, K=128]
// then inter-chunk scan; correction Y += exp(cum_i) * C . hprev^T [MFMA].
//
// R1: k_ssd_a LDS XOR-swizzle (chunk ^= row&7, LOW 3 bits = bank bits). Kept.
// R2 FAILED (reverted): 512-thread ssd_a blocks didn't raise occupancy.
// R3: hot-path expf -> __expf: ssd_a 77->68us.
// R4: GEMM XCD-chunked swizzle + small-dim-fastest; k_cum wave-parallel scan.
// R5a FAILED: fused ssd_c+rmsnorm had (1) gv[16] reg array -> spills (VGPR
// 208, WRITE 180MB), (2) swizzle XOR at chunk bits 3..5 = ABOVE bank field ->
// 8-way conflicts (7.6e6), (3) 1 block/CU. 121us vs 63us unfused.
// R5b kept: k_scan loads all 64 chunk values before the serial scan.
// R6: k_ssd_cn v2: corr-only LDS (plain writes, correct low-bit swizzle),
// gate+ssq pass writes g back to LDS (no gv[] regs), scale pass re-reads;
// y/z global access interleaved (lg=k*4+q) for 64B-contiguous coalescing.
//
// Workspace (bytes), total 264,046,592 (~252 MiB):
//   F16    f16 [65536,256]    [0,          33,554,432)
//   ipw16  f16 [1156,256]     [33,554,432, 34,146,304)
//   opw16  f16 [256,512]      [34,146,304, 34,408,448)
//   dtbuf  f32 [8,4,8192]     [34,408,448, 35,457,024)
//   cumbuf f32 [8,4,8192]     [35,457,024, 36,505,600)
//   wbuf   f32 [8,4,8192]     [36,505,600, 37,554,176)
//   xT     f16 [512,65536]    [37,554,176, 104,663,040)  live: gemm -> ssd_a
//   XCt    f16 [512,32768]    [104,663,040,138,217,472)  live: conv -> ssd_a
//   bcLr   f16 [32768,128]    [138,217,472,146,606,080)  raw left B/C
//   bcR    f16 [32768,128]    [146,606,080,154,994,688)  raw right B/C
//   bcL    f16 [32768,128]    [154,994,688,163,383,296)  conv'd left B/C
//   ybuf   f16 [65536,512]    [163,383,296,230,492,160)
//   states f16 [8,64,4,128,64][230,492,160,264,046,592)
//   zbuf   f16 [65536,512]    alias over dead xT
// ---------------------------------------------------------------------------

typedef _Float16 f16;
typedef __attribute__((ext_vector_type(8))) _Float16 f16x8;
typedef __attribute__((ext_vector_type(4))) _Float16 f16x4;
typedef __attribute__((ext_vector_type(4))) float f32x4;

__device__ __forceinline__ float fexpf(float v) { return __expf(v); }
__device__ __forceinline__ float siluf(float v) { return v / (1.0f + __expf(-v)); }

__device__ __forceinline__ void gload_lds16(const void* g, void* l) {
    __builtin_amdgcn_global_load_lds(
        (const __attribute__((address_space(1))) void*)g,
        (__attribute__((address_space(3))) void*)l, 16, 0, 0);
}

// ---------------- fp32 -> f16 cast ------------------------------------------
__global__ __launch_bounds__(256) void k_cvt(
    const float* __restrict__ s, f16* __restrict__ d, int n)
{
    int i = blockIdx.x * 256 + threadIdx.x;
    if (i < n) d[i] = (f16)s[i];
}

// ---------------- downsample: 4x4/4 conv, 3->256 ch, NCHW -> (row, c) f16 ---
__global__ __launch_bounds__(256) void k_downsample(
    const float* __restrict__ limg, const float* __restrict__ rimg,
    const float* __restrict__ w, const float* __restrict__ bias,
    f16* __restrict__ F)
{
    __shared__ float wS[12288];   // [c][48]
    __shared__ float pS[768];     // [pix][48]
    int t = threadIdx.x;
    int bid = blockIdx.x;               // og(8) | oy(64) | b(4) | side(2)
    int og = bid & 7;
    int oy = (bid >> 3) & 63;
    int b  = (bid >> 9) & 3;
    int side = bid >> 11;
    const float* img = side ? rimg : limg;

    for (int e = t * 4; e < 12288; e += 1024)
        *(float4*)(wS + e) = *(const float4*)(w + e);

    int ox0 = og * 16;
    for (int f = t; f < 768; f += 256) {
        int kx = f & 3, pix = (f >> 2) & 15, ky = (f >> 6) & 3, ci = f >> 8;
        float v = img[((b * 3 + ci) * 256 + oy * 4 + ky) * 512 + ox0 * 4 + pix * 4 + kx];
        pS[pix * 48 + ci * 16 + ky * 4 + kx] = v;
    }
    __syncthreads();

    int c = t;
    float wreg[48];
#pragma unroll
    for (int q = 0; q < 12; q++) {
        float4 v = *(const float4*)(wS + c * 48 + q * 4);
        wreg[q * 4 + 0] = v.x; wreg[q * 4 + 1] = v.y;
        wreg[q * 4 + 2] = v.z; wreg[q * 4 + 3] = v.w;
    }
    float bv = bias[c];
    long base = ((long)(side * 32768 + b * 8192 + oy * 128 + ox0)) * 256 + c;
    for (int pix = 0; pix < 16; pix++) {
        float acc = bv;
#pragma unroll
        for (int q = 0; q < 12; q++) {
            float4 p4 = *(const float4*)(pS + pix * 48 + q * 4);
            acc += wreg[q * 4 + 0] * p4.x + wreg[q * 4 + 1] * p4.y
                 + wreg[q * 4 + 2] * p4.z + wreg[q * 4 + 3] * p4.w;
        }
        F[base + (long)pix * 256] = (f16)acc;
    }
}

// ---------------- f16 MFMA NT GEMM: C[m,n] = sum_k A[m,k]*B[n,k] ------------
// 128x128 tile, BK=64, 4 waves (2x2), each wave 4x4 frags of 16x16x32.
// lda = ldb = K. Output rows >= split go to CR (row-split).
// Grid is (m_tiles, n_tiles); requires (m_tiles*n_tiles) % 8 == 0.
// R4: XCD-chunked bijective swizzle + small-tile-dim-fastest enumeration so
// consecutive blocks on one XCD reuse the large operand tile in its L2.
template<typename TO>
__global__ __launch_bounds__(256) void k_gemm_mfma(
    const f16* __restrict__ A, const f16* __restrict__ B,
    TO* __restrict__ CL, TO* __restrict__ CR, int K, int ldc, int split)
{
    __shared__ f16 As[128 * 64];
    __shared__ f16 Bs[128 * 64];
    int t = threadIdx.x;
    int w = t >> 6, lane = t & 63;
    int wm = w >> 1, wn = w & 1;

    int gx = gridDim.x, gy = gridDim.y;          // (m_tiles, n_tiles)
    int nwg = gx * gy;
    int orig = blockIdx.y * gx + blockIdx.x;     // dispatch order (x fastest)
    int swz = (orig & 7) * (nwg >> 3) + (orig >> 3);   // chunked XCD swizzle
    int mt, nt;
    if (gx <= gy) { mt = swz % gx; nt = swz / gx; }    // share B-tile
    else          { nt = swz % gy; mt = swz / gy; }    // share A-tile
    long m0 = (long)mt * 128;
    int n0 = nt * 128;

    f32x4 acc[4][4] = {};

    const f16* ga = A + (m0 + w * 8 + (lane >> 3)) * K + (lane & 7) * 8;
    const f16* gb = B + ((long)n0 + w * 8 + (lane >> 3)) * K + (lane & 7) * 8;
    f16* la = As + (w * 8) * 64;
    f16* lb = Bs + (w * 8) * 64;

    for (int kk = 0; kk < K; kk += 64) {
#pragma unroll
        for (int i = 0; i < 4; i++) {
            gload_lds16(ga + (long)i * 32 * K + kk, la + i * 32 * 64);
            gload_lds16(gb + (long)i * 32 * K + kk, lb + i * 32 * 64);
        }
        __syncthreads();

        const f16* pa = As + (wm * 64 + (lane & 15)) * 64 + (lane >> 4) * 8;
        const f16* pb = Bs + (wn * 64 + (lane & 15)) * 64 + (lane >> 4) * 8;
#pragma unroll
        for (int kb = 0; kb < 2; kb++) {
            f16x8 af[4], bf[4];
#pragma unroll
            for (int r = 0; r < 4; r++)
                af[r] = *(const f16x8*)(pa + r * 16 * 64 + kb * 32);
#pragma unroll
            for (int cn = 0; cn < 4; cn++)
                bf[cn] = *(const f16x8*)(pb + cn * 16 * 64 + kb * 32);
#pragma unroll
            for (int r = 0; r < 4; r++)
#pragma unroll
                for (int cn = 0; cn < 4; cn++)
                    acc[r][cn] = __builtin_amdgcn_mfma_f32_16x16x32_f16(
                        af[r], bf[cn], acc[r][cn], 0, 0, 0);
        }
        __syncthreads();
    }

    int rb = (lane >> 4) * 4;
    int cb = lane & 15;
#pragma unroll
    for (int r = 0; r < 4; r++) {
        long mrow = m0 + wm * 64 + r * 16 + rb;
#pragma unroll
        for (int reg = 0; reg < 4; reg++) {
            long row = mrow + reg;
            TO* Cp = (row < split) ? CL + row * ldc : CR + (row - split) * ldc;
#pragma unroll
            for (int cn = 0; cn < 4; cn++)
                Cp[n0 + wn * 64 + cn * 16 + cb] = (TO)acc[r][cn][reg];
        }
    }
}

// ---------------- dt: fp32 dot of F16 row with W rows 1152..1155, softplus --
__global__ __launch_bounds__(256) void k_dt(
    const f16* __restrict__ F, const float* __restrict__ W,
    const float* __restrict__ dt_bias, float* __restrict__ dtbuf)
{
    int t = threadIdx.x;
    int wv = t >> 6, lane = t & 63;
    long m = (long)blockIdx.x * 4 + wv;     // 0..65535
    f16x4 fv = *(const f16x4*)(F + m * 256 + lane * 4);
    float dots[4];
#pragma unroll
    for (int h = 0; h < 4; h++) {
        float4 w4 = *(const float4*)(W + (long)(1152 + h) * 256 + lane * 4);
        float d = (float)fv[0] * w4.x + (float)fv[1] * w4.y
                + (float)fv[2] * w4.z + (float)fv[3] * w4.w;
#pragma unroll
        for (int off = 32; off; off >>= 1) d += __shfl_down(d, off, 64);
        dots[h] = d;
    }
    if (lane == 0) {
        long sb = m >> 13;                  // side*4 + b
        long l = m & 8191;
#pragma unroll
        for (int h = 0; h < 4; h++) {
            float v = dots[h] + dt_bias[h];
            float sp = (v > 20.0f) ? v : log1pf(expf(v));
            dtbuf[(sb * 4 + h) * 8192 + l] = sp;
        }
    }
}

// ---------------- per-chunk cumsum of dt*A, and w = dt*exp(cumL-cum) --------
// R4: wave-parallel. One wave per (sb,h,c) group of 128 elements; lane holds
// 2 elems (float2), 6-step shuffle inclusive scan, fused w computation.
__global__ __launch_bounds__(256) void k_cum(
    const float* __restrict__ dtbuf, const float* __restrict__ A_log,
    float* __restrict__ cumbuf, float* __restrict__ wbuf)
{
    int wv = threadIdx.x >> 6, lane = threadIdx.x & 63;
    int g = blockIdx.x * 4 + wv;                // 2048 = sb(8)*h(4)*c(64)
    int c = g & 63, h = (g >> 6) & 3, sb = g >> 8;
    float A = -__expf(A_log[h]);
    long base = ((long)sb * 4 + h) * 8192 + c * 128;
    float2 d = *(const float2*)(dtbuf + base + lane * 2);
    float a0 = d.x * A;
    float p = a0 + d.y * A;                     // in-lane pair sum
    float s = p;
#pragma unroll
    for (int off = 1; off < 64; off <<= 1) {
        float v = __shfl_up(s, off, 64);
        if (lane >= off) s += v;
    }
    float excl = s - p;
    float c0 = excl + a0, c1 = excl + p;
    float cl = __shfl(s, 63, 64);               // chunk total
    *(float2*)(cumbuf + base + lane * 2) = make_float2(c0, c1);
    *(float2*)(wbuf + base + lane * 2) =
        make_float2(d.x * __expf(cl - c0), d.y * __expf(cl - c1));
}

// ---------------- causal conv1d on transposed x (contiguous along L) --------
__global__ __launch_bounds__(256) void k_conv_x(
    const f16* __restrict__ xT, const float* __restrict__ cw,
    const float* __restrict__ cb, f16* __restrict__ XCt)
{
    int bid = blockIdx.x;               // c(512) | b(4) | tile(4)
    int c = bid >> 4;
    int b = (bid >> 2) & 3;
    int tile = bid & 3;
    int l0 = tile * 2048 + threadIdx.x * 8;
    const f16* row = xT + (long)c * 65536 + b * 8192;   // left cols only
    float w0 = cw[c * 4 + 0], w1 = cw[c * 4 + 1],
          w2 = cw[c * 4 + 2], w3 = cw[c * 4 + 3];
    float bv = cb[c];
    float xv[11];
    f16x8 v = *(const f16x8*)(row + l0);
#pragma unroll
    for (int q = 0; q < 8; q++) xv[3 + q] = (float)v[q];
    if (l0 > 0) {
        xv[0] = (float)row[l0 - 3];
        xv[1] = (float)row[l0 - 2];
        xv[2] = (float)row[l0 - 1];
    } else { xv[0] = xv[1] = xv[2] = 0.f; }
    f16x8 o;
#pragma unroll
    for (int q = 0; q < 8; q++) {
        float acc = bv + w0 * xv[q] + w1 * xv[q + 1] + w2 * xv[q + 2] + w3 * xv[q + 3];
        o[q] = (f16)siluf(acc);
    }
    *(f16x8*)(XCt + (long)c * 32768 + b * 8192 + l0) = o;
}

// ---------------- causal conv1d on left B/C (row-major [l][128]) ------------
__global__ __launch_bounds__(256) void k_conv_bc(
    const f16* __restrict__ bcLr, const float* __restrict__ cw,
    const float* __restrict__ cb, f16* __restrict__ bcL)
{
    long idx = (long)blockIdx.x * 256 + threadIdx.x;    // 32768*128
    int n = (int)(idx & 127);
    long m = idx >> 7;
    int l = (int)(m & 8191);
    float acc = cb[512 + n];
#pragma unroll
    for (int k = 0; k < 4; k++) {
        int j = l - 3 + k;
        if (j >= 0) acc += cw[(512 + n) * 4 + k] * (float)bcLr[(m - 3 + k) * 128 + n];
    }
    bcL[m * 128 + n] = (f16)siluf(acc);
}

// ---------------- SSD phase A: MFMA chunked formulation ---------------------
// LDS 64 KB: Xs[p=128][j=128] (32KB) | Cs[i=128][n=64] (16KB) | Bs[j=128][n=64]
// (16KB); Ms[i=128][j=128] overlays Cs+Bs after G.
// All tiles XOR-swizzled in 16B chunks: phys_chunk = log_chunk ^ (row & 7).
// global_load_lds writes linearly -> inverse swizzle applied to the per-lane
// GLOBAL source column; ds_read fragments and Ms write/read apply the XOR.
__global__ __launch_bounds__(256) void k_ssd_a(
    const f16* __restrict__ xT, const f16* __restrict__ XCt,
    const f16* __restrict__ bcR, const f16* __restrict__ bcL,
    const float* __restrict__ dtbuf, const float* __restrict__ cumbuf,
    const float* __restrict__ wbuf, const float* __restrict__ Dvec,
    f16* __restrict__ ybuf, f16* __restrict__ states)
{
    extern __shared__ f16 sm[];
    f16* Xs = sm;            // [p][j]  swizzled
    f16* Cs = sm + 16384;    // [i][n]  swizzled
    f16* Bs = sm + 24576;    // [j][n]  swizzled
    f16* Ms = sm + 16384;    // [i][j]  overlay, swizzled

    int t = threadIdx.x;
    int w = t >> 6, lane = t & 63;
    int quad = lane >> 4, l16 = lane & 15;
    int wm = w >> 1, wn = w & 1;
    int bid = blockIdx.x;
    int side = bid >> 10, rem = bid & 1023;
    int b = rem >> 8, c = (rem >> 2) & 63, h = rem & 3;
    long l0 = (long)b * 8192 + c * 128;
    long dtbase = ((long)(side * 4 + b) * 4 + h) * 8192 + c * 128;

    const f16* Xg; long ldx;
    const f16 *Bg, *Cg;
    if (side == 0) {
        Xg = xT + (long)(h * 128) * 65536 + 32768 + l0; ldx = 65536;
        Bg = bcR + l0 * 128;
        Cg = bcL + l0 * 128 + 64;
    } else {
        Xg = XCt + (long)(h * 128) * 32768 + l0;        ldx = 32768;
        Bg = bcL + l0 * 128;
        Cg = bcR + l0 * 128 + 64;
    }

    int sw8 = l16 & 7;   // row&7 for all MFMA-phase fragment rows (row%16==l16)

    // stage X (4 rows/call): lane (quad,l16) lands at LDS (row r0+quad, chunk
    // l16) -> source column chunk = l16 ^ (row&7)
#pragma unroll
    for (int q = 0; q < 8; q++) {
        int r0 = w * 32 + q * 4;
        int R = r0 + quad;
        gload_lds16(Xg + (long)R * ldx + ((l16 ^ (R & 7)) << 3), Xs + r0 * 128);
    }
    // stage C and B (8 rows/call): lane lands at (row r0+(lane>>3), chunk
    // lane&7) -> source chunk = (lane&7) ^ (row&7)
#pragma unroll
    for (int q = 0; q < 4; q++) {
        int r0 = w * 32 + q * 8;
        int R = r0 + (lane >> 3);
        int cc = ((lane & 7) ^ (R & 7)) << 3;
        gload_lds16(Cg + (long)R * 128 + cc, Cs + r0 * 64);
        gload_lds16(Bg + (long)R * 128 + cc, Bs + r0 * 64);
    }

    float cum_i[16], cum_j[4], dt_j[4];
#pragma unroll
    for (int r = 0; r < 4; r++)
#pragma unroll
        for (int reg = 0; reg < 4; reg++)
            cum_i[r * 4 + reg] = cumbuf[dtbase + wm * 64 + r * 16 + quad * 4 + reg];
#pragma unroll
    for (int cn = 0; cn < 4; cn++) {
        int j = wn * 64 + cn * 16 + l16;
        cum_j[cn] = cumbuf[dtbase + j];
        dt_j[cn] = dtbuf[dtbase + j];
    }
    float Dh = Dvec[h];
    __syncthreads();

    // G = C . B^T  (K=64)
    f32x4 g[4][4] = {};
#pragma unroll
    for (int kb = 0; kb < 2; kb++) {
        f16x8 af[4], bf[4];
#pragma unroll
        for (int r = 0; r < 4; r++)
            af[r] = *(const f16x8*)(Cs + (wm * 64 + r * 16 + l16) * 64
                                       + (((quad + kb * 4) ^ sw8) << 3));
#pragma unroll
        for (int cn = 0; cn < 4; cn++)
            bf[cn] = *(const f16x8*)(Bs + (wn * 64 + cn * 16 + l16) * 64
                                        + (((quad + kb * 4) ^ sw8) << 3));
#pragma unroll
        for (int r = 0; r < 4; r++)
#pragma unroll
            for (int cn = 0; cn < 4; cn++)
                g[r][cn] = __builtin_amdgcn_mfma_f32_16x16x32_f16(
                    af[r], bf[cn], g[r][cn], 0, 0, 0);
    }
    __syncthreads();

    // M = mask(G)*exp*dt (+D on diagonal), write f16 to LDS (overlay Cs/Bs)
#pragma unroll
    for (int r = 0; r < 4; r++)
#pragma unroll
        for (int cn = 0; cn < 4; cn++)
#pragma unroll
            for (int reg = 0; reg < 4; reg++) {
                int i = wm * 64 + r * 16 + quad * 4 + reg;
                int j = wn * 64 + cn * 16 + l16;
                float v = 0.f;
                if (i >= j)
                    v = g[r][cn][reg] * fexpf(cum_i[r * 4 + reg] - cum_j[cn]) * dt_j[cn];
                if (i == j) v += Dh;
                Ms[i * 128 + ((((j >> 3) ^ (i & 7))) << 3) + (j & 7)] = (f16)v;
            }
    __syncthreads();

    // Y = M . X   (K=128): A=Ms[i][j], B=Xs[p][j]
    f32x4 y[4][4] = {};
#pragma unroll
    for (int kb = 0; kb < 4; kb++) {
        f16x8 af[4], bf[4];
#pragma unroll
        for (int r = 0; r < 4; r++)
            af[r] = *(const f16x8*)(Ms + (wm * 64 + r * 16 + l16) * 128
                                       + (((quad + kb * 4) ^ sw8) << 3));
#pragma unroll
        for (int cn = 0; cn < 4; cn++)
            bf[cn] = *(const f16x8*)(Xs + (wn * 64 + cn * 16 + l16) * 128
                                        + (((quad + kb * 4) ^ sw8) << 3));
#pragma unroll
        for (int r = 0; r < 4; r++)
#pragma unroll
            for (int cn = 0; cn < 4; cn++)
                y[r][cn] = __builtin_amdgcn_mfma_f32_16x16x32_f16(
                    af[r], bf[cn], y[r][cn], 0, 0, 0);
    }
    long ybase = (long)side * 32768 + l0;
#pragma unroll
    for (int r = 0; r < 4; r++)
#pragma unroll
        for (int reg = 0; reg < 4; reg++) {
            int i = wm * 64 + r * 16 + quad * 4 + reg;
#pragma unroll
            for (int cn = 0; cn < 4; cn++) {
                int p = wn * 64 + cn * 16 + l16;
                ybuf[(ybase + i) * 512 + h * 128 + p] = (f16)y[r][cn][reg];
            }
        }

    // states = X^T(weighted B): A=Xs[p][j], B-frags built from global B * w_j
    f32x4 s[4][2] = {};
#pragma unroll
    for (int kb = 0; kb < 4; kb++) {
        float wj[8];
#pragma unroll
        for (int jj = 0; jj < 8; jj++)
            wj[jj] = wbuf[dtbase + kb * 32 + quad * 8 + jj];
        f16x8 af[4], bf[2];
#pragma unroll
        for (int r = 0; r < 4; r++)
            af[r] = *(const f16x8*)(Xs + (wm * 64 + r * 16 + l16) * 128
                                       + (((quad + kb * 4) ^ sw8) << 3));
#pragma unroll
        for (int cn = 0; cn < 2; cn++) {
            int n = wn * 32 + cn * 16 + l16;
#pragma unroll
            for (int jj = 0; jj < 8; jj++) {
                int j = kb * 32 + quad * 8 + jj;
                bf[cn][jj] = (f16)((float)Bg[(long)j * 128 + n] * wj[jj]);
            }
        }
#pragma unroll
        for (int r = 0; r < 4; r++)
#pragma unroll
            for (int cn = 0; cn < 2; cn++)
                s[r][cn] = __builtin_amdgcn_mfma_f32_16x16x32_f16(
                    af[r], bf[cn], s[r][cn], 0, 0, 0);
    }
    long sbase = (((long)(side * 4 + b) * 64 + c) * 4 + h) * 128;
#pragma unroll
    for (int r = 0; r < 4; r++)
#pragma unroll
        for (int reg = 0; reg < 4; reg++) {
            int p = wm * 64 + r * 16 + quad * 4 + reg;
#pragma unroll
            for (int cn = 0; cn < 2; cn++) {
                int n = wn * 32 + cn * 16 + l16;
                states[(sbase + p) * 64 + n] = (f16)s[r][cn][reg];
            }
        }
}

// ---------------- inter-chunk scan over 64 chunks (in place, fp16) ----------
// R5: load all 64 chunk-values into regs first (independent loads pipeline
// under vmcnt) instead of a 64-deep dependent load->store chain.
__global__ __launch_bounds__(256) void k_scan(
    f16* __restrict__ states, const float* __restrict__ cumbuf)
{
    long g = (long)blockIdx.x * 256 + threadIdx.x;   // 262144 threads
    int n = (int)(g & 63);
    int p = (int)((g >> 6) & 127);
    int h = (int)((g >> 13) & 3);
    int sb = (int)(g >> 15);                         // side*4+b
    long sbase = (((long)sb * 256 + h) * 128 + p) * 64 + n;   // c=0
    long cbase = ((long)sb * 4 + h) * 8192 + 127;
    float sv[64];
#pragma unroll
    for (int c = 0; c < 64; c++)
        sv[c] = (float)states[sbase + (long)c * 32768];
    float hr = 0.f;
#pragma unroll
    for (int c = 0; c < 64; c++) {
        states[sbase + (long)c * 32768] = (f16)hr;   // hprev for chunk c
        hr = hr * fexpf(cumbuf[cbase + (long)c * 128]) + sv[c];
    }
}

// ---------------- fused SSD phase C + gated rmsnorm (v2) --------------------
// Per block: (side,b,chunk,half) = 64 rows x 512 cols. 256 threads, 4 waves.
// LDS 64KB: cS f16 [64 rows][64 chunks of 16B], phys_chunk = chunk ^ (row&7)
// (XOR in LOW 3 chunk bits = bank bits 4..6 of the byte address).
// P1: corr = exp(cum_i) * C(64x64).hprev^T(128x64) [MFMA] -> plain writes
//     into cS (no y staging, no RMW).
// P2a: per row (4 threads/row, interleaved cols lg=k*4+q for 64B-coalesced
//     global reads): g = (y + corr)*silu(z); accumulate ssq; write g back to
//     own cS slots (no register array -> no spills).
// P2b: sc = rsqrt(mean+eps); re-read own slots, scale by sc*nw, store ybuf.
__global__ __launch_bounds__(256) void k_ssd_cn(
    const f16* __restrict__ bcR, const f16* __restrict__ bcL,
    const f16* __restrict__ states, const float* __restrict__ cumbuf,
    const f16* __restrict__ zbuf, const float* __restrict__ nw,
    f16* __restrict__ ybuf)
{
    extern __shared__ f16 cS[];   // [64][512] swizzled
    int t = threadIdx.x;
    int w = t >> 6, lane = t & 63;
    int quad = lane >> 4, l16 = lane & 15;
    int wm = w >> 1, wn = w & 1;
    int bid = blockIdx.x;                 // sb(8) | c(64) | half(2)
    int sb = bid >> 7, c = (bid >> 1) & 63, half = bid & 1;
    int side = sb >> 2, b = sb & 3;
    long lrow0 = (long)b * 8192 + c * 128 + half * 64;   // row in per-side bufs
    long grow0 = (long)side * 32768 + lrow0;             // row in ybuf/zbuf

    // ---- P1: per-head correction MFMA -> cS (plain swizzled writes) ----
    const f16* Cg = ((side == 0) ? bcL : bcR) + lrow0 * 128 + 64;
    f16x8 af[2][2];
#pragma unroll
    for (int r = 0; r < 2; r++)
#pragma unroll
        for (int kb = 0; kb < 2; kb++)
            af[r][kb] = *(const f16x8*)(Cg + (long)(wm * 32 + r * 16 + l16) * 128
                                           + quad * 8 + kb * 32);
#pragma unroll
    for (int h = 0; h < 4; h++) {
        long stile = (((long)sb * 64 + c) * 4 + h) * 8192;
        f32x4 acc[2][4] = {};
#pragma unroll
        for (int kb = 0; kb < 2; kb++) {
            f16x8 bf[4];
#pragma unroll
            for (int cn = 0; cn < 4; cn++)
                bf[cn] = *(const f16x8*)(states + stile
                            + (long)(wn * 64 + cn * 16 + l16) * 64 + quad * 8 + kb * 32);
#pragma unroll
            for (int r = 0; r < 2; r++)
#pragma unroll
                for (int cn = 0; cn < 4; cn++)
                    acc[r][cn] = __builtin_amdgcn_mfma_f32_16x16x32_f16(
                        af[r][kb], bf[cn], acc[r][cn], 0, 0, 0);
        }
        long dtb = ((long)sb * 4 + h) * 8192 + c * 128 + half * 64;
#pragma unroll
        for (int r = 0; r < 2; r++)
#pragma unroll
            for (int reg = 0; reg < 4; reg++) {
                int i = wm * 32 + r * 16 + quad * 4 + reg;
                float ex = fexpf(cumbuf[dtb + i]);
#pragma unroll
                for (int cn = 0; cn < 4; cn++) {
                    int col = h * 128 + wn * 64 + cn * 16 + l16;
                    int addr = i * 512 + (((col >> 3) ^ (i & 7)) << 3) + (col & 7);
                    cS[addr] = (f16)(ex * acc[r][cn][reg]);
                }
            }
    }
    __syncthreads();

    // ---- P2a: g = (y + corr) * silu(z); ssq; write g to own slots ----
    int row = t >> 2, q = t & 3;
    int rs = row & 7;
    long grow = grow0 + row;
    const f16* yrow = ybuf + grow * 512;
    const f16* zrow = zbuf + grow * 512;
    float ssq = 0.f;
#pragma unroll
    for (int k = 0; k < 16; k++) {
        int lg = k * 4 + q;
        f16* slot = cS + row * 512 + ((lg ^ rs) << 3);
        f16x8 cv = *(const f16x8*)slot;
        f16x8 yv = *(const f16x8*)(yrow + lg * 8);
        f16x8 zv = *(const f16x8*)(zrow + lg * 8);
        f16x8 gg;
#pragma unroll
        for (int qq = 0; qq < 8; qq++) {
            float gf = ((float)yv[qq] + (float)cv[qq]) * siluf((float)zv[qq]);
            gg[qq] = (f16)gf;
            ssq += gf * gf;
        }
        *(f16x8*)slot = gg;
    }
    ssq += __shfl_xor(ssq, 1, 64);
    ssq += __shfl_xor(ssq, 2, 64);
    float sc = rsqrtf(ssq * (1.0f / 512.0f) + 1e-5f);

    // ---- P2b: scale by sc*nw, write ybuf (same-thread slots, no barrier) ----
    f16* orow = ybuf + grow * 512;
#pragma unroll
    for (int k = 0; k < 16; k++) {
        int lg = k * 4 + q;
        f16x8 gg = *(const f16x8*)(cS + row * 512 + ((lg ^ rs) << 3));
        float4 w0 = *(const float4*)(nw + lg * 8);
        float4 w1 = *(const float4*)(nw + lg * 8 + 4);
        f16x8 o;
        o[0] = (f16)((float)gg[0] * sc * w0.x);
        o[1] = (f16)((float)gg[1] * sc * w0.y);
        o[2] = (f16)((float)gg[2] * sc * w0.z);
        o[3] = (f16)((float)gg[3] * sc * w0.w);
        o[4] = (f16)((float)gg[4] * sc * w1.x);
        o[5] = (f16)((float)gg[5] * sc * w1.y);
        o[6] = (f16)((float)gg[6] * sc * w1.z);
        o[7] = (f16)((float)gg[7] * sc * w1.w);
        *(f16x8*)(orow + lg * 8) = o;
    }
}

// ---------------------------------------------------------------------------
extern "C" void kernel_launch(void* const* d_in, const int* in_sizes, int n_in,
                              void* d_out, int out_size, void* d_ws, size_t ws_size,
                              hipStream_t stream)
{
    (void)in_sizes; (void)n_in; (void)out_size; (void)ws_size;
    const float* limg = (const float*)d_in[0];
    const float* rimg = (const float*)d_in[1];
    const float* dsw  = (const float*)d_in[2];
    const float* dsb  = (const float*)d_in[3];
    const float* ipw  = (const float*)d_in[4];
    const float* cw   = (const float*)d_in[5];
    const float* cb   = (const float*)d_in[6];
    const float* dtb  = (const float*)d_in[7];
    const float* alog = (const float*)d_in[8];
    const float* Dv   = (const float*)d_in[9];
    const float* nw   = (const float*)d_in[10];
    const float* opw  = (const float*)d_in[11];
    float* out = (float*)d_out;

    char* ws = (char*)d_ws;
    f16*   F16    = (f16*)  (ws + 0);
    f16*   ipw16  = (f16*)  (ws + 33554432);
    f16*   opw16  = (f16*)  (ws + 34146304);
    float* dtbuf  = (float*)(ws + 34408448);
    float* cumbuf = (float*)(ws + 35457024);
    float* wbuf   = (float*)(ws + 36505600);
    f16*   xT     = (f16*)  (ws + 37554176);
    f16*   XCt    = (f16*)  (ws + 104663040);
    f16*   bcLr   = (f16*)  (ws + 138217472);
    f16*   bcR    = (f16*)  (ws + 146606080);
    f16*   bcL    = (f16*)  (ws + 154994688);
    f16*   ybuf   = (f16*)  (ws + 163383296);
    f16*   states = (f16*)  (ws + 230492160);
    f16*   zbuf   = xT;                          // alias (xT dead after ssd_a)

    const int BIG = 1 << 30;
    k_downsample<<<4096, 256, 0, stream>>>(limg, rimg, dsw, dsb, F16);
    k_cvt<<<1156, 256, 0, stream>>>(ipw, ipw16, 1156 * 256);
    k_cvt<<<512, 256, 0, stream>>>(opw, opw16, 256 * 512);
    // B/C columns (weights rows 1024..1151): out [l][128], split L/R
    k_gemm_mfma<f16><<<dim3(512, 1), 256, 0, stream>>>(
        F16, ipw16 + 1024 * 256, bcLr, bcR, 256, 128, 32768);
    // x columns TRANSPOSED: A=weights rows 512..1023, B=F16 -> xT[512][65536]
    k_gemm_mfma<f16><<<dim3(4, 512), 256, 0, stream>>>(
        ipw16 + 512 * 256, F16, xT, xT, 256, 65536, BIG);
    k_dt<<<16384, 256, 0, stream>>>(F16, ipw, dtb, dtbuf);
    k_cum<<<512, 256, 0, stream>>>(dtbuf, alog, cumbuf, wbuf);
    k_conv_x<<<8192, 256, 0, stream>>>(xT, cw, cb, XCt);
    k_conv_bc<<<16384, 256, 0, stream>>>(bcLr, cw, cb, bcL);
    k_ssd_a<<<2048, 256, 65536, stream>>>(
        xT, XCt, bcR, bcL, dtbuf, cumbuf, wbuf, Dv, ybuf, states);
    k_scan<<<1024, 256, 0, stream>>>(states, cumbuf);
    // z = F @ ipw[0:512]^T (into region freed by xT) -- before fused epilogue
    k_gemm_mfma<f16><<<dim3(512, 4), 256, 0, stream>>>(
        F16, ipw16, zbuf, zbuf, 256, 512, BIG);
    // fused: y += exp(cum)*C.hprev^T ; y = rmsnorm(y*silu(z))*nw
    k_ssd_cn<<<1024, 256, 65536, stream>>>(
        bcR, bcL, states, cumbuf, zbuf, nw, ybuf);
    // out = y @ opw^T (fp32 out), split L/R halves of d_out
    k_gemm_mfma<float><<<dim3(512, 2), 256, 0, stream>>>(
        ybuf, opw16, out, out + (long)32768 * 256, 512, 256, 32768);
}

// Round 7
// 497.389 us; speedup vs baseline: 1.1241x; 1.0225x over previous
//
#include <hip/hip_runtime.h>
#include <hip/hip_fp16.h>
#include <math.h>

// ---------------------------------------------------------------------------
// Mamba2 stereo SSD block. All GEMM-shaped work on f16 MFMA; fp32 dt/cum/exp.
// B=4, L=8192 (64x128), D_MODEL=256, D_INNER=512, NHEADS=4, HEADDIM=128,
// D_STATE=64, CONV_DIM=640, CHUNK=128, NCHUNK=64.
//
// SSD per-tile formulation (side,b,chunk,head):
//   G = C (128x64) . B^T (64x128)            [MFMA, K=64]
//   M_ij = (i>=j) ? G_ij*exp(cum_i-cum_j)*dt_j : 0 ;  M_ii += D_h
//   Y = M (128x128) . X (128lx128p)          [MFMA, K=128]  (D*x folded in M)
//   states_pn = sum_j X_jp * B_jn * dt_j*exp(cumL-cum_j)   [MFMA, K=128]
// then inter-chunk scan; correction Y += exp(cum_i) * C . hprev^T [MFMA].
//
// R1: k_ssd_a LDS XOR-swizzle (chunk ^= row&7, LOW 3 bits = bank bits). Kept.
// R2 FAILED (reverted): 512-thread ssd_a blocks didn't raise occupancy.
// R3: hot-path expf -> __expf: ssd_a 77->68us.
// R4: GEMM XCD-chunked swizzle + small-dim-fastest; k_cum wave-parallel scan.
// R5a FAILED: fused ssd_c+rmsnorm v1: reg-array spills + swizzle above bank
// bits + 1 block/CU -> 121us. R5b kept: k_scan preloads 64 values.
// R6: k_ssd_cn v2 fixed all three (VGPR 128, WRITE 65MB, conflicts 1e6) ->
// 72us, but still latency-bound at 19% occupancy (64KB LDS = 2 blocks/CU).
// R7: k_ssd_cn v3: 32-row blocks (32KB LDS, grid 2048) -> 4 blocks/CU.
// P1: one wave per head (32x128, acc[2][8]); P2: 8 threads/row. XCD-chunked
// work swizzle keeps the 4 quarter-blocks of a chunk on one XCD so the
// states tile re-reads hit that XCD's L2.
//
// Workspace (bytes), total 264,046,592 (~252 MiB):
//   F16    f16 [65536,256]    [0,          33,554,432)
//   ipw16  f16 [1156,256]     [33,554,432, 34,146,304)
//   opw16  f16 [256,512]      [34,146,304, 34,408,448)
//   dtbuf  f32 [8,4,8192]     [34,408,448, 35,457,024)
//   cumbuf f32 [8,4,8192]     [35,457,024, 36,505,600)
//   wbuf   f32 [8,4,8192]     [36,505,600, 37,554,176)
//   xT     f16 [512,65536]    [37,554,176, 104,663,040)  live: gemm -> ssd_a
//   XCt    f16 [512,32768]    [104,663,040,138,217,472)  live: conv -> ssd_a
//   bcLr   f16 [32768,128]    [138,217,472,146,606,080)  raw left B/C
//   bcR    f16 [32768,128]    [146,606,080,154,994,688)  raw right B/C
//   bcL    f16 [32768,128]    [154,994,688,163,383,296)  conv'd left B/C
//   ybuf   f16 [65536,512]    [163,383,296,230,492,160)
//   states f16 [8,64,4,128,64][230,492,160,264,046,592)
//   zbuf   f16 [65536,512]    alias over dead xT
// ---------------------------------------------------------------------------

typedef _Float16 f16;
typedef __attribute__((ext_vector_type(8))) _Float16 f16x8;
typedef __attribute__((ext_vector_type(4))) _Float16 f16x4;
typedef __attribute__((ext_vector_type(4))) float f32x4;

__device__ __forceinline__ float fexpf(float v) { return __expf(v); }
__device__ __forceinline__ float siluf(float v) { return v / (1.0f + __expf(-v)); }

__device__ __forceinline__ void gload_lds16(const void* g, void* l) {
    __builtin_amdgcn_global_load_lds(
        (const __attribute__((address_space(1))) void*)g,
        (__attribute__((address_space(3))) void*)l, 16, 0, 0);
}

// ---------------- fp32 -> f16 cast ------------------------------------------
__global__ __launch_bounds__(256) void k_cvt(
    const float* __restrict__ s, f16* __restrict__ d, int n)
{
    int i = blockIdx.x * 256 + threadIdx.x;
    if (i < n) d[i] = (f16)s[i];
}

// ---------------- downsample: 4x4/4 conv, 3->256 ch, NCHW -> (row, c) f16 ---
__global__ __launch_bounds__(256) void k_downsample(
    const float* __restrict__ limg, const float* __restrict__ rimg,
    const float* __restrict__ w, const float* __restrict__ bias,
    f16* __restrict__ F)
{
    __shared__ float wS[12288];   // [c][48]
    __shared__ float pS[768];     // [pix][48]
    int t = threadIdx.x;
    int bid = blockIdx.x;               // og(8) | oy(64) | b(4) | side(2)
    int og = bid & 7;
    int oy = (bid >> 3) & 63;
    int b  = (bid >> 9) & 3;
    int side = bid >> 11;
    const float* img = side ? rimg : limg;

    for (int e = t * 4; e < 12288; e += 1024)
        *(float4*)(wS + e) = *(const float4*)(w + e);

    int ox0 = og * 16;
    for (int f = t; f < 768; f += 256) {
        int kx = f & 3, pix = (f >> 2) & 15, ky = (f >> 6) & 3, ci = f >> 8;
        float v = img[((b * 3 + ci) * 256 + oy * 4 + ky) * 512 + ox0 * 4 + pix * 4 + kx];
        pS[pix * 48 + ci * 16 + ky * 4 + kx] = v;
    }
    __syncthreads();

    int c = t;
    float wreg[48];
#pragma unroll
    for (int q = 0; q < 12; q++) {
        float4 v = *(const float4*)(wS + c * 48 + q * 4);
        wreg[q * 4 + 0] = v.x; wreg[q * 4 + 1] = v.y;
        wreg[q * 4 + 2] = v.z; wreg[q * 4 + 3] = v.w;
    }
    float bv = bias[c];
    long base = ((long)(side * 32768 + b * 8192 + oy * 128 + ox0)) * 256 + c;
    for (int pix = 0; pix < 16; pix++) {
        float acc = bv;
#pragma unroll
        for (int q = 0; q < 12; q++) {
            float4 p4 = *(const float4*)(pS + pix * 48 + q * 4);
            acc += wreg[q * 4 + 0] * p4.x + wreg[q * 4 + 1] * p4.y
                 + wreg[q * 4 + 2] * p4.z + wreg[q * 4 + 3] * p4.w;
        }
        F[base + (long)pix * 256] = (f16)acc;
    }
}

// ---------------- f16 MFMA NT GEMM: C[m,n] = sum_k A[m,k]*B[n,k] ------------
// 128x128 tile, BK=64, 4 waves (2x2), each wave 4x4 frags of 16x16x32.
// lda = ldb = K. Output rows >= split go to CR (row-split).
// Grid is (m_tiles, n_tiles); requires (m_tiles*n_tiles) % 8 == 0.
// R4: XCD-chunked bijective swizzle + small-tile-dim-fastest enumeration so
// consecutive blocks on one XCD reuse the large operand tile in its L2.
template<typename TO>
__global__ __launch_bounds__(256) void k_gemm_mfma(
    const f16* __restrict__ A, const f16* __restrict__ B,
    TO* __restrict__ CL, TO* __restrict__ CR, int K, int ldc, int split)
{
    __shared__ f16 As[128 * 64];
    __shared__ f16 Bs[128 * 64];
    int t = threadIdx.x;
    int w = t >> 6, lane = t & 63;
    int wm = w >> 1, wn = w & 1;

    int gx = gridDim.x, gy = gridDim.y;          // (m_tiles, n_tiles)
    int nwg = gx * gy;
    int orig = blockIdx.y * gx + blockIdx.x;     // dispatch order (x fastest)
    int swz = (orig & 7) * (nwg >> 3) + (orig >> 3);   // chunked XCD swizzle
    int mt, nt;
    if (gx <= gy) { mt = swz % gx; nt = swz / gx; }    // share B-tile
    else          { nt = swz % gy; mt = swz / gy; }    // share A-tile
    long m0 = (long)mt * 128;
    int n0 = nt * 128;

    f32x4 acc[4][4] = {};

    const f16* ga = A + (m0 + w * 8 + (lane >> 3)) * K + (lane & 7) * 8;
    const f16* gb = B + ((long)n0 + w * 8 + (lane >> 3)) * K + (lane & 7) * 8;
    f16* la = As + (w * 8) * 64;
    f16* lb = Bs + (w * 8) * 64;

    for (int kk = 0; kk < K; kk += 64) {
#pragma unroll
        for (int i = 0; i < 4; i++) {
            gload_lds16(ga + (long)i * 32 * K + kk, la + i * 32 * 64);
            gload_lds16(gb + (long)i * 32 * K + kk, lb + i * 32 * 64);
        }
        __syncthreads();

        const f16* pa = As + (wm * 64 + (lane & 15)) * 64 + (lane >> 4) * 8;
        const f16* pb = Bs + (wn * 64 + (lane & 15)) * 64 + (lane >> 4) * 8;
#pragma unroll
        for (int kb = 0; kb < 2; kb++) {
            f16x8 af[4], bf[4];
#pragma unroll
            for (int r = 0; r < 4; r++)
                af[r] = *(const f16x8*)(pa + r * 16 * 64 + kb * 32);
#pragma unroll
            for (int cn = 0; cn < 4; cn++)
                bf[cn] = *(const f16x8*)(pb + cn * 16 * 64 + kb * 32);
#pragma unroll
            for (int r = 0; r < 4; r++)
#pragma unroll
                for (int cn = 0; cn < 4; cn++)
                    acc[r][cn] = __builtin_amdgcn_mfma_f32_16x16x32_f16(
                        af[r], bf[cn], acc[r][cn], 0, 0, 0);
        }
        __syncthreads();
    }

    int rb = (lane >> 4) * 4;
    int cb = lane & 15;
#pragma unroll
    for (int r = 0; r < 4; r++) {
        long mrow = m0 + wm * 64 + r * 16 + rb;
#pragma unroll
        for (int reg = 0; reg < 4; reg++) {
            long row = mrow + reg;
            TO* Cp = (row < split) ? CL + row * ldc : CR + (row - split) * ldc;
#pragma unroll
            for (int cn = 0; cn < 4; cn++)
                Cp[n0 + wn * 64 + cn * 16 + cb] = (TO)acc[r][cn][reg];
        }
    }
}

// ---------------- dt: fp32 dot of F16 row with W rows 1152..1155, softplus --
__global__ __launch_bounds__(256) void k_dt(
    const f16* __restrict__ F, const float* __restrict__ W,
    const float* __restrict__ dt_bias, float* __restrict__ dtbuf)
{
    int t = threadIdx.x;
    int wv = t >> 6, lane = t & 63;
    long m = (long)blockIdx.x * 4 + wv;     // 0..65535
    f16x4 fv = *(const f16x4*)(F + m * 256 + lane * 4);
    float dots[4];
#pragma unroll
    for (int h = 0; h < 4; h++) {
        float4 w4 = *(const float4*)(W + (long)(1152 + h) * 256 + lane * 4);
        float d = (float)fv[0] * w4.x + (float)fv[1] * w4.y
                + (float)fv[2] * w4.z + (float)fv[3] * w4.w;
#pragma unroll
        for (int off = 32; off; off >>= 1) d += __shfl_down(d, off, 64);
        dots[h] = d;
    }
    if (lane == 0) {
        long sb = m >> 13;                  // side*4 + b
        long l = m & 8191;
#pragma unroll
        for (int h = 0; h < 4; h++) {
            float v = dots[h] + dt_bias[h];
            float sp = (v > 20.0f) ? v : log1pf(expf(v));
            dtbuf[(sb * 4 + h) * 8192 + l] = sp;
        }
    }
}

// ---------------- per-chunk cumsum of dt*A, and w = dt*exp(cumL-cum) --------
// R4: wave-parallel. One wave per (sb,h,c) group of 128 elements; lane holds
// 2 elems (float2), 6-step shuffle inclusive scan, fused w computation.
__global__ __launch_bounds__(256) void k_cum(
    const float* __restrict__ dtbuf, const float* __restrict__ A_log,
    float* __restrict__ cumbuf, float* __restrict__ wbuf)
{
    int wv = threadIdx.x >> 6, lane = threadIdx.x & 63;
    int g = blockIdx.x * 4 + wv;                // 2048 = sb(8)*h(4)*c(64)
    int c = g & 63, h = (g >> 6) & 3, sb = g >> 8;
    float A = -__expf(A_log[h]);
    long base = ((long)sb * 4 + h) * 8192 + c * 128;
    float2 d = *(const float2*)(dtbuf + base + lane * 2);
    float a0 = d.x * A;
    float p = a0 + d.y * A;                     // in-lane pair sum
    float s = p;
#pragma unroll
    for (int off = 1; off < 64; off <<= 1) {
        float v = __shfl_up(s, off, 64);
        if (lane >= off) s += v;
    }
    float excl = s - p;
    float c0 = excl + a0, c1 = excl + p;
    float cl = __shfl(s, 63, 64);               // chunk total
    *(float2*)(cumbuf + base + lane * 2) = make_float2(c0, c1);
    *(float2*)(wbuf + base + lane * 2) =
        make_float2(d.x * __expf(cl - c0), d.y * __expf(cl - c1));
}

// ---------------- causal conv1d on transposed x (contiguous along L) --------
__global__ __launch_bounds__(256) void k_conv_x(
    const f16* __restrict__ xT, const float* __restrict__ cw,
    const float* __restrict__ cb, f16* __restrict__ XCt)
{
    int bid = blockIdx.x;               // c(512) | b(4) | tile(4)
    int c = bid >> 4;
    int b = (bid >> 2) & 3;
    int tile = bid & 3;
    int l0 = tile * 2048 + threadIdx.x * 8;
    const f16* row = xT + (long)c * 65536 + b * 8192;   // left cols only
    float w0 = cw[c * 4 + 0], w1 = cw[c * 4 + 1],
          w2 = cw[c * 4 + 2], w3 = cw[c * 4 + 3];
    float bv = cb[c];
    float xv[11];
    f16x8 v = *(const f16x8*)(row + l0);
#pragma unroll
    for (int q = 0; q < 8; q++) xv[3 + q] = (float)v[q];
    if (l0 > 0) {
        xv[0] = (float)row[l0 - 3];
        xv[1] = (float)row[l0 - 2];
        xv[2] = (float)row[l0 - 1];
    } else { xv[0] = xv[1] = xv[2] = 0.f; }
    f16x8 o;
#pragma unroll
    for (int q = 0; q < 8; q++) {
        float acc = bv + w0 * xv[q] + w1 * xv[q + 1] + w2 * xv[q + 2] + w3 * xv[q + 3];
        o[q] = (f16)siluf(acc);
    }
    *(f16x8*)(XCt + (long)c * 32768 + b * 8192 + l0) = o;
}

// ---------------- causal conv1d on left B/C (row-major [l][128]) ------------
__global__ __launch_bounds__(256) void k_conv_bc(
    const f16* __restrict__ bcLr, const float* __restrict__ cw,
    const float* __restrict__ cb, f16* __restrict__ bcL)
{
    long idx = (long)blockIdx.x * 256 + threadIdx.x;    // 32768*128
    int n = (int)(idx & 127);
    long m = idx >> 7;
    int l = (int)(m & 8191);
    float acc = cb[512 + n];
#pragma unroll
    for (int k = 0; k < 4; k++) {
        int j = l - 3 + k;
        if (j >= 0) acc += cw[(512 + n) * 4 + k] * (float)bcLr[(m - 3 + k) * 128 + n];
    }
    bcL[m * 128 + n] = (f16)siluf(acc);
}

// ---------------- SSD phase A: MFMA chunked formulation ---------------------
// LDS 64 KB: Xs[p=128][j=128] (32KB) | Cs[i=128][n=64] (16KB) | Bs[j=128][n=64]
// (16KB); Ms[i=128][j=128] overlays Cs+Bs after G.
// All tiles XOR-swizzled in 16B chunks: phys_chunk = log_chunk ^ (row & 7).
// global_load_lds writes linearly -> inverse swizzle applied to the per-lane
// GLOBAL source column; ds_read fragments and Ms write/read apply the XOR.
__global__ __launch_bounds__(256) void k_ssd_a(
    const f16* __restrict__ xT, const f16* __restrict__ XCt,
    const f16* __restrict__ bcR, const f16* __restrict__ bcL,
    const float* __restrict__ dtbuf, const float* __restrict__ cumbuf,
    const float* __restrict__ wbuf, const float* __restrict__ Dvec,
    f16* __restrict__ ybuf, f16* __restrict__ states)
{
    extern __shared__ f16 sm[];
    f16* Xs = sm;            // [p][j]  swizzled
    f16* Cs = sm + 16384;    // [i][n]  swizzled
    f16* Bs = sm + 24576;    // [j][n]  swizzled
    f16* Ms = sm + 16384;    // [i][j]  overlay, swizzled

    int t = threadIdx.x;
    int w = t >> 6, lane = t & 63;
    int quad = lane >> 4, l16 = lane & 15;
    int wm = w >> 1, wn = w & 1;
    int bid = blockIdx.x;
    int side = bid >> 10, rem = bid & 1023;
    int b = rem >> 8, c = (rem >> 2) & 63, h = rem & 3;
    long l0 = (long)b * 8192 + c * 128;
    long dtbase = ((long)(side * 4 + b) * 4 + h) * 8192 + c * 128;

    const f16* Xg; long ldx;
    const f16 *Bg, *Cg;
    if (side == 0) {
        Xg = xT + (long)(h * 128) * 65536 + 32768 + l0; ldx = 65536;
        Bg = bcR + l0 * 128;
        Cg = bcL + l0 * 128 + 64;
    } else {
        Xg = XCt + (long)(h * 128) * 32768 + l0;        ldx = 32768;
        Bg = bcL + l0 * 128;
        Cg = bcR + l0 * 128 + 64;
    }

    int sw8 = l16 & 7;   // row&7 for all MFMA-phase fragment rows (row%16==l16)

    // stage X (4 rows/call): lane (quad,l16) lands at LDS (row r0+quad, chunk
    // l16) -> source column chunk = l16 ^ (row&7)
#pragma unroll
    for (int q = 0; q < 8; q++) {
        int r0 = w * 32 + q * 4;
        int R = r0 + quad;
        gload_lds16(Xg + (long)R * ldx + ((l16 ^ (R & 7)) << 3), Xs + r0 * 128);
    }
    // stage C and B (8 rows/call): lane lands at (row r0+(lane>>3), chunk
    // lane&7) -> source chunk = (lane&7) ^ (row&7)
#pragma unroll
    for (int q = 0; q < 4; q++) {
        int r0 = w * 32 + q * 8;
        int R = r0 + (lane >> 3);
        int cc = ((lane & 7) ^ (R & 7)) << 3;
        gload_lds16(Cg + (long)R * 128 + cc, Cs + r0 * 64);
        gload_lds16(Bg + (long)R * 128 + cc, Bs + r0 * 64);
    }

    float cum_i[16], cum_j[4], dt_j[4];
#pragma unroll
    for (int r = 0; r < 4; r++)
#pragma unroll
        for (int reg = 0; reg < 4; reg++)
            cum_i[r * 4 + reg] = cumbuf[dtbase + wm * 64 + r * 16 + quad * 4 + reg];
#pragma unroll
    for (int cn = 0; cn < 4; cn++) {
        int j = wn * 64 + cn * 16 + l16;
        cum_j[cn] = cumbuf[dtbase + j];
        dt_j[cn] = dtbuf[dtbase + j];
    }
    float Dh = Dvec[h];
    __syncthreads();

    // G = C . B^T  (K=64)
    f32x4 g[4][4] = {};
#pragma unroll
    for (int kb = 0; kb < 2; kb++) {
        f16x8 af[4], bf[4];
#pragma unroll
        for (int r = 0; r < 4; r++)
            af[r] = *(const f16x8*)(Cs + (wm * 64 + r * 16 + l16) * 64
                                       + (((quad + kb * 4) ^ sw8) << 3));
#pragma unroll
        for (int cn = 0; cn < 4; cn++)
            bf[cn] = *(const f16x8*)(Bs + (wn * 64 + cn * 16 + l16) * 64
                                        + (((quad + kb * 4) ^ sw8) << 3));
#pragma unroll
        for (int r = 0; r < 4; r++)
#pragma unroll
            for (int cn = 0; cn < 4; cn++)
                g[r][cn] = __builtin_amdgcn_mfma_f32_16x16x32_f16(
                    af[r], bf[cn], g[r][cn], 0, 0, 0);
    }
    __syncthreads();

    // M = mask(G)*exp*dt (+D on diagonal), write f16 to LDS (overlay Cs/Bs)
#pragma unroll
    for (int r = 0; r < 4; r++)
#pragma unroll
        for (int cn = 0; cn < 4; cn++)
#pragma unroll
            for (int reg = 0; reg < 4; reg++) {
                int i = wm * 64 + r * 16 + quad * 4 + reg;
                int j = wn * 64 + cn * 16 + l16;
                float v = 0.f;
                if (i >= j)
                    v = g[r][cn][reg] * fexpf(cum_i[r * 4 + reg] - cum_j[cn]) * dt_j[cn];
                if (i == j) v += Dh;
                Ms[i * 128 + ((((j >> 3) ^ (i & 7))) << 3) + (j & 7)] = (f16)v;
            }
    __syncthreads();

    // Y = M . X   (K=128): A=Ms[i][j], B=Xs[p][j]
    f32x4 y[4][4] = {};
#pragma unroll
    for (int kb = 0; kb < 4; kb++) {
        f16x8 af[4], bf[4];
#pragma unroll
        for (int r = 0; r < 4; r++)
            af[r] = *(const f16x8*)(Ms + (wm * 64 + r * 16 + l16) * 128
                                       + (((quad + kb * 4) ^ sw8) << 3));
#pragma unroll
        for (int cn = 0; cn < 4; cn++)
            bf[cn] = *(const f16x8*)(Xs + (wn * 64 + cn * 16 + l16) * 128
                                        + (((quad + kb * 4) ^ sw8) << 3));
#pragma unroll
        for (int r = 0; r < 4; r++)
#pragma unroll
            for (int cn = 0; cn < 4; cn++)
                y[r][cn] = __builtin_amdgcn_mfma_f32_16x16x32_f16(
                    af[r], bf[cn], y[r][cn], 0, 0, 0);
    }
    long ybase = (long)side * 32768 + l0;
#pragma unroll
    for (int r = 0; r < 4; r++)
#pragma unroll
        for (int reg = 0; reg < 4; reg++) {
            int i = wm * 64 + r * 16 + quad * 4 + reg;
#pragma unroll
            for (int cn = 0; cn < 4; cn++) {
                int p = wn * 64 + cn * 16 + l16;
                ybuf[(ybase + i) * 512 + h * 128 + p] = (f16)y[r][cn][reg];
            }
        }

    // states = X^T(weighted B): A=Xs[p][j], B-frags built from global B * w_j
    f32x4 s[4][2] = {};
#pragma unroll
    for (int kb = 0; kb < 4; kb++) {
        float wj[8];
#pragma unroll
        for (int jj = 0; jj < 8; jj++)
            wj[jj] = wbuf[dtbase + kb * 32 + quad * 8 + jj];
        f16x8 af[4], bf[2];
#pragma unroll
        for (int r = 0; r < 4; r++)
            af[r] = *(const f16x8*)(Xs + (wm * 64 + r * 16 + l16) * 128
                                       + (((quad + kb * 4) ^ sw8) << 3));
#pragma unroll
        for (int cn = 0; cn < 2; cn++) {
            int n = wn * 32 + cn * 16 + l16;
#pragma unroll
            for (int jj = 0; jj < 8; jj++) {
                int j = kb * 32 + quad * 8 + jj;
                bf[cn][jj] = (f16)((float)Bg[(long)j * 128 + n] * wj[jj]);
            }
        }
#pragma unroll
        for (int r = 0; r < 4; r++)
#pragma unroll
            for (int cn = 0; cn < 2; cn++)
                s[r][cn] = __builtin_amdgcn_mfma_f32_16x16x32_f16(
                    af[r], bf[cn], s[r][cn], 0, 0, 0);
    }
    long sbase = (((long)(side * 4 + b) * 64 + c) * 4 + h) * 128;
#pragma unroll
    for (int r = 0; r < 4; r++)
#pragma unroll
        for (int reg = 0; reg < 4; reg++) {
            int p = wm * 64 + r * 16 + quad * 4 + reg;
#pragma unroll
            for (int cn = 0; cn < 2; cn++) {
                int n = wn * 32 + cn * 16 + l16;
                states[(sbase + p) * 64 + n] = (f16)s[r][cn][reg];
            }
        }
}

// ---------------- inter-chunk scan over 64 chunks (in place, fp16) ----------
// R5: load all 64 chunk-values into regs first (independent loads pipeline
// under vmcnt) instead of a 64-deep dependent load->store chain.
__global__ __launch_bounds__(256) void k_scan(
    f16* __restrict__ states, const float* __restrict__ cumbuf)
{
    long g = (long)blockIdx.x * 256 + threadIdx.x;   // 262144 threads
    int n = (int)(g & 63);
    int p = (int)((g >> 6) & 127);
    int h = (int)((g >> 13) & 3);
    int sb = (int)(g >> 15);                         // side*4+b
    long sbase = (((long)sb * 256 + h) * 128 + p) * 64 + n;   // c=0
    long cbase = ((long)sb * 4 + h) * 8192 + 127;
    float sv[64];
#pragma unroll
    for (int c = 0; c < 64; c++)
        sv[c] = (float)states[sbase + (long)c * 32768];
    float hr = 0.f;
#pragma unroll
    for (int c = 0; c < 64; c++) {
        states[sbase + (long)c * 32768] = (f16)hr;   // hprev for chunk c
        hr = hr * fexpf(cumbuf[cbase + (long)c * 128]) + sv[c];
    }
}

// ---------------- fused SSD phase C + gated rmsnorm (v3) --------------------
// Per block: (side,b,chunk,quarter) = 32 rows x 512 cols. 256 threads, 4
// waves, 32KB LDS -> 4 blocks/CU (vs 2 at 64KB in v2).
// Work id XCD-chunk-swizzled so the 4 quarter-blocks of one (sb,c) stay on
// one XCD and the shared 64KB states tile hits its L2.
// LDS: cS f16 [32 rows][64 chunks of 16B], phys_chunk = chunk ^ (row&7).
// P1: wave w = head w: corr = exp(cum_i) * C(32x64).hprev^T(128x64) [MFMA,
//     acc[2][8]] -> plain swizzled writes into cS cols h*128..h*128+127.
// P2a: 8 threads/row: g = (y + corr)*silu(z); ssq over 8 lanes (3 shfl_xor);
//     write g back to own cS slots (no reg arrays -> no spills).
// P2b: scale by rsqrt(mean+eps)*nw, store ybuf.
__global__ __launch_bounds__(256) void k_ssd_cn(
    const f16* __restrict__ bcR, const f16* __restrict__ bcL,
    const f16* __restrict__ states, const float* __restrict__ cumbuf,
    const f16* __restrict__ zbuf, const float* __restrict__ nw,
    f16* __restrict__ ybuf)
{
    extern __shared__ f16 cS[];   // [32][512] swizzled
    int t = threadIdx.x;
    int w = t >> 6, lane = t & 63;
    int quad = lane >> 4, l16 = lane & 15;
    int bid = blockIdx.x;                     // 2048 blocks
    int work = (bid & 7) * 256 + (bid >> 3);  // XCD-chunked bijective swizzle
    int sb = work >> 8, rem = work & 255;     // sb(8) | c(64) | quarter(4)
    int c = rem >> 2, quarter = rem & 3;
    int side = sb >> 2, b = sb & 3;
    long lrow0 = (long)b * 8192 + c * 128 + quarter * 32;  // row in side bufs
    long grow0 = (long)side * 32768 + lrow0;               // row in ybuf/zbuf

    // ---- P1: wave w computes head w's correction (32 rows x 128 cols) ----
    const f16* Cg = ((side == 0) ? bcL : bcR) + lrow0 * 128 + 64;
    int h = w;
    long stile = (((long)sb * 64 + c) * 4 + h) * 8192;
    long dtb = ((long)sb * 4 + h) * 8192 + c * 128 + quarter * 32;
    f16x8 af[2][2];
#pragma unroll
    for (int r = 0; r < 2; r++)
#pragma unroll
        for (int kb = 0; kb < 2; kb++)
            af[r][kb] = *(const f16x8*)(Cg + (long)(r * 16 + l16) * 128
                                           + quad * 8 + kb * 32);
    f32x4 acc[2][8] = {};
#pragma unroll
    for (int kb = 0; kb < 2; kb++) {
        f16x8 bf[8];
#pragma unroll
        for (int cn = 0; cn < 8; cn++)
            bf[cn] = *(const f16x8*)(states + stile
                        + (long)(cn * 16 + l16) * 64 + quad * 8 + kb * 32);
#pragma unroll
        for (int r = 0; r < 2; r++)
#pragma unroll
            for (int cn = 0; cn < 8; cn++)
                acc[r][cn] = __builtin_amdgcn_mfma_f32_16x16x32_f16(
                    af[r][kb], bf[cn], acc[r][cn], 0, 0, 0);
    }
#pragma unroll
    for (int r = 0; r < 2; r++)
#pragma unroll
        for (int reg = 0; reg < 4; reg++) {
            int i = r * 16 + quad * 4 + reg;
            float ex = fexpf(cumbuf[dtb + i]);
#pragma unroll
            for (int cn = 0; cn < 8; cn++) {
                int col = h * 128 + cn * 16 + l16;
                int addr = i * 512 + (((col >> 3) ^ (i & 7)) << 3) + (col & 7);
                cS[addr] = (f16)(ex * acc[r][cn][reg]);
            }
        }
    __syncthreads();

    // ---- P2a: g = (y + corr) * silu(z); ssq; write g to own slots ----
    int row = t >> 3, q8 = t & 7;     // 8 threads/row, 32 rows
    int rs = row & 7;
    long grow = grow0 + row;
    const f16* yrow = ybuf + grow * 512;
    const f16* zrow = zbuf + grow * 512;
    float ssq = 0.f;
#pragma unroll
    for (int k = 0; k < 8; k++) {
        int lg = k * 8 + q8;
        f16* slot = cS + row * 512 + ((lg ^ rs) << 3);
        f16x8 cv = *(const f16x8*)slot;
        f16x8 yv = *(const f16x8*)(yrow + lg * 8);
        f16x8 zv = *(const f16x8*)(zrow + lg * 8);
        f16x8 gg;
#pragma unroll
        for (int qq = 0; qq < 8; qq++) {
            float gf = ((float)yv[qq] + (float)cv[qq]) * siluf((float)zv[qq]);
            gg[qq] = (f16)gf;
            ssq += gf * gf;
        }
        *(f16x8*)slot = gg;
    }
    ssq += __shfl_xor(ssq, 1, 64);
    ssq += __shfl_xor(ssq, 2, 64);
    ssq += __shfl_xor(ssq, 4, 64);
    float sc = rsqrtf(ssq * (1.0f / 512.0f) + 1e-5f);

    // ---- P2b: scale by sc*nw, write ybuf (same-thread slots, no barrier) ----
    f16* orow = ybuf + grow * 512;
#pragma unroll
    for (int k = 0; k < 8; k++) {
        int lg = k * 8 + q8;
        f16x8 gg = *(const f16x8*)(cS + row * 512 + ((lg ^ rs) << 3));
        float4 w0 = *(const float4*)(nw + lg * 8);
        float4 w1 = *(const float4*)(nw + lg * 8 + 4);
        f16x8 o;
        o[0] = (f16)((float)gg[0] * sc * w0.x);
        o[1] = (f16)((float)gg[1] * sc * w0.y);
        o[2] = (f16)((float)gg[2] * sc * w0.z);
        o[3] = (f16)((float)gg[3] * sc * w0.w);
        o[4] = (f16)((float)gg[4] * sc * w1.x);
        o[5] = (f16)((float)gg[5] * sc * w1.y);
        o[6] = (f16)((float)gg[6] * sc * w1.z);
        o[7] = (f16)((float)gg[7] * sc * w1.w);
        *(f16x8*)(orow + lg * 8) = o;
    }
}

// ---------------------------------------------------------------------------
extern "C" void kernel_launch(void* const* d_in, const int* in_sizes, int n_in,
                              void* d_out, int out_size, void* d_ws, size_t ws_size,
                              hipStream_t stream)
{
    (void)in_sizes; (void)n_in; (void)out_size; (void)ws_size;
    const float* limg = (const float*)d_in[0];
    const float* rimg = (const float*)d_in[1];
    const float* dsw  = (const float*)d_in[2];
    const float* dsb  = (const float*)d_in[3];
    const float* ipw  = (const float*)d_in[4];
    const float* cw   = (const float*)d_in[5];
    const float* cb   = (const float*)d_in[6];
    const float* dtb  = (const float*)d_in[7];
    const float* alog = (const float*)d_in[8];
    const float* Dv   = (const float*)d_in[9];
    const float* nw   = (const float*)d_in[10];
    const float* opw  = (const float*)d_in[11];
    float* out = (float*)d_out;

    char* ws = (char*)d_ws;
    f16*   F16    = (f16*)  (ws + 0);
    f16*   ipw16  = (f16*)  (ws + 33554432);
    f16*   opw16  = (f16*)  (ws + 34146304);
    float* dtbuf  = (float*)(ws + 34408448);
    float* cumbuf = (float*)(ws + 35457024);
    float* wbuf   = (float*)(ws + 36505600);
    f16*   xT     = (f16*)  (ws + 37554176);
    f16*   XCt    = (f16*)  (ws + 104663040);
    f16*   bcLr   = (f16*)  (ws + 138217472);
    f16*   bcR    = (f16*)  (ws + 146606080);
    f16*   bcL    = (f16*)  (ws + 154994688);
    f16*   ybuf   = (f16*)  (ws + 163383296);
    f16*   states = (f16*)  (ws + 230492160);
    f16*   zbuf   = xT;                          // alias (xT dead after ssd_a)

    const int BIG = 1 << 30;
    k_downsample<<<4096, 256, 0, stream>>>(limg, rimg, dsw, dsb, F16);
    k_cvt<<<1156, 256, 0, stream>>>(ipw, ipw16, 1156 * 256);
    k_cvt<<<512, 256, 0, stream>>>(opw, opw16, 256 * 512);
    // B/C columns (weights rows 1024..1151): out [l][128], split L/R
    k_gemm_mfma<f16><<<dim3(512, 1), 256, 0, stream>>>(
        F16, ipw16 + 1024 * 256, bcLr, bcR, 256, 128, 32768);
    // x columns TRANSPOSED: A=weights rows 512..1023, B=F16 -> xT[512][65536]
    k_gemm_mfma<f16><<<dim3(4, 512), 256, 0, stream>>>(
        ipw16 + 512 * 256, F16, xT, xT, 256, 65536, BIG);
    k_dt<<<16384, 256, 0, stream>>>(F16, ipw, dtb, dtbuf);
    k_cum<<<512, 256, 0, stream>>>(dtbuf, alog, cumbuf, wbuf);
    k_conv_x<<<8192, 256, 0, stream>>>(xT, cw, cb, XCt);
    k_conv_bc<<<16384, 256, 0, stream>>>(bcLr, cw, cb, bcL);
    k_ssd_a<<<2048, 256, 65536, stream>>>(
        xT, XCt, bcR, bcL, dtbuf, cumbuf, wbuf, Dv, ybuf, states);
    k_scan<<<1024, 256, 0, stream>>>(states, cumbuf);
    // z = F @ ipw[0:512]^T (into region freed by xT) -- before fused epilogue
    k_gemm_mfma<f16><<<dim3(512, 4), 256, 0, stream>>>(
        F16, ipw16, zbuf, zbuf, 256, 512, BIG);
    // fused: y += exp(cum)*C.hprev^T ; y = rmsnorm(y*silu(z))*nw
    k_ssd_cn<<<2048, 256, 32768, stream>>>(
        bcR, bcL, states, cumbuf, zbuf, nw, ybuf);
    // out = y @ opw^T (fp32 out), split L/R halves of d_out
    k_gemm_mfma<float><<<dim3(512, 2), 256, 0, stream>>>(
        ybuf, opw16, out, out + (long)32768 * 256, 512, 256, 32768);
}

// Round 8
// 489.677 us; speedup vs baseline: 1.1418x; 1.0158x over previous
//
#include <hip/hip_runtime.h>
#include <hip/hip_fp16.h>
#include <math.h>

// ---------------------------------------------------------------------------
// Mamba2 stereo SSD block. All GEMM-shaped work on f16 MFMA; fp32 dt/cum/exp.
// B=4, L=8192 (64x128), D_MODEL=256, D_INNER=512, NHEADS=4, HEADDIM=128,
// D_STATE=64, CONV_DIM=640, CHUNK=128, NCHUNK=64.
//
// SSD per-tile formulation (side,b,chunk,head):
//   G = C (128x64) . B^T (64x128)            [MFMA, K=64]
//   M_ij = (i>=j) ? G_ij*exp(cum_i-cum_j)*dt_j : 0 ;  M_ii += D_h
//   Y = M (128x128) . X (128lx128p)          [MFMA, K=128]  (D*x folded in M)
//   states_pn = sum_j X_jp * B_jn * dt_j*exp(cumL-cum_j)   [MFMA, K=128]
// then inter-chunk scan; correction Y += exp(cum_i) * C . hprev^T [MFMA].
//
// R1: k_ssd_a LDS XOR-swizzle (chunk ^= row&7, LOW 3 bits = bank bits). Kept.
// R2 FAILED (reverted): 512-thread ssd_a blocks didn't raise occupancy.
// R3: hot-path expf -> __expf: ssd_a 77->68us.
// R4: GEMM XCD-chunked swizzle + small-dim-fastest; k_cum wave-parallel scan.
// R5a FAILED: fused ssd_c+rmsnorm v1 (spills + wrong swizzle bits + 1 blk/CU).
// R5b kept: k_scan preloads 64 values. R6: k_ssd_cn v2 fixed v1 -> 72us.
// R7: k_ssd_cn v3 32-row blocks (32KB LDS -> 4 blk/CU) -> out of top-5. Kept.
// R8: k_ssd_a 64KB -> 48KB LDS (3 blk/CU, 12 waves/CU vs 8):
//   - Cs staging dropped; G-phase A-operand reads C fragments from global
//     (k_ssd_c-proven pattern; C tile is L2/L3-resident).
//   - M precomputed into packed f16 regs (mv[8], frees g before y allocs),
//     then Y = M.X done in two K=64 j-halves through a 16KB Ms overlay on
//     the dead Bs region (wn==half waves dump, barrier, all accumulate).
//
// Workspace (bytes), total 264,046,592 (~252 MiB):
//   F16    f16 [65536,256]    [0,          33,554,432)
//   ipw16  f16 [1156,256]     [33,554,432, 34,146,304)
//   opw16  f16 [256,512]      [34,146,304, 34,408,448)
//   dtbuf  f32 [8,4,8192]     [34,408,448, 35,457,024)
//   cumbuf f32 [8,4,8192]     [35,457,024, 36,505,600)
//   wbuf   f32 [8,4,8192]     [36,505,600, 37,554,176)
//   xT     f16 [512,65536]    [37,554,176, 104,663,040)  live: gemm -> ssd_a
//   XCt    f16 [512,32768]    [104,663,040,138,217,472)  live: conv -> ssd_a
//   bcLr   f16 [32768,128]    [138,217,472,146,606,080)  raw left B/C
//   bcR    f16 [32768,128]    [146,606,080,154,994,688)  raw right B/C
//   bcL    f16 [32768,128]    [154,994,688,163,383,296)  conv'd left B/C
//   ybuf   f16 [65536,512]    [163,383,296,230,492,160)
//   states f16 [8,64,4,128,64][230,492,160,264,046,592)
//   zbuf   f16 [65536,512]    alias over dead xT
// ---------------------------------------------------------------------------

typedef _Float16 f16;
typedef __attribute__((ext_vector_type(8))) _Float16 f16x8;
typedef __attribute__((ext_vector_type(4))) _Float16 f16x4;
typedef __attribute__((ext_vector_type(4))) float f32x4;

__device__ __forceinline__ float fexpf(float v) { return __expf(v); }
__device__ __forceinline__ float siluf(float v) { return v / (1.0f + __expf(-v)); }

__device__ __forceinline__ void gload_lds16(const void* g, void* l) {
    __builtin_amdgcn_global_load_lds(
        (const __attribute__((address_space(1))) void*)g,
        (__attribute__((address_space(3))) void*)l, 16, 0, 0);
}

// ---------------- fp32 -> f16 cast ------------------------------------------
__global__ __launch_bounds__(256) void k_cvt(
    const float* __restrict__ s, f16* __restrict__ d, int n)
{
    int i = blockIdx.x * 256 + threadIdx.x;
    if (i < n) d[i] = (f16)s[i];
}

// ---------------- downsample: 4x4/4 conv, 3->256 ch, NCHW -> (row, c) f16 ---
__global__ __launch_bounds__(256) void k_downsample(
    const float* __restrict__ limg, const float* __restrict__ rimg,
    const float* __restrict__ w, const float* __restrict__ bias,
    f16* __restrict__ F)
{
    __shared__ float wS[12288];   // [c][48]
    __shared__ float pS[768];     // [pix][48]
    int t = threadIdx.x;
    int bid = blockIdx.x;               // og(8) | oy(64) | b(4) | side(2)
    int og = bid & 7;
    int oy = (bid >> 3) & 63;
    int b  = (bid >> 9) & 3;
    int side = bid >> 11;
    const float* img = side ? rimg : limg;

    for (int e = t * 4; e < 12288; e += 1024)
        *(float4*)(wS + e) = *(const float4*)(w + e);

    int ox0 = og * 16;
    for (int f = t; f < 768; f += 256) {
        int kx = f & 3, pix = (f >> 2) & 15, ky = (f >> 6) & 3, ci = f >> 8;
        float v = img[((b * 3 + ci) * 256 + oy * 4 + ky) * 512 + ox0 * 4 + pix * 4 + kx];
        pS[pix * 48 + ci * 16 + ky * 4 + kx] = v;
    }
    __syncthreads();

    int c = t;
    float wreg[48];
#pragma unroll
    for (int q = 0; q < 12; q++) {
        float4 v = *(const float4*)(wS + c * 48 + q * 4);
        wreg[q * 4 + 0] = v.x; wreg[q * 4 + 1] = v.y;
        wreg[q * 4 + 2] = v.z; wreg[q * 4 + 3] = v.w;
    }
    float bv = bias[c];
    long base = ((long)(side * 32768 + b * 8192 + oy * 128 + ox0)) * 256 + c;
    for (int pix = 0; pix < 16; pix++) {
        float acc = bv;
#pragma unroll
        for (int q = 0; q < 12; q++) {
            float4 p4 = *(const float4*)(pS + pix * 48 + q * 4);
            acc += wreg[q * 4 + 0] * p4.x + wreg[q * 4 + 1] * p4.y
                 + wreg[q * 4 + 2] * p4.z + wreg[q * 4 + 3] * p4.w;
        }
        F[base + (long)pix * 256] = (f16)acc;
    }
}

// ---------------- f16 MFMA NT GEMM: C[m,n] = sum_k A[m,k]*B[n,k] ------------
// 128x128 tile, BK=64, 4 waves (2x2), each wave 4x4 frags of 16x16x32.
// lda = ldb = K. Output rows >= split go to CR (row-split).
// Grid is (m_tiles, n_tiles); requires (m_tiles*n_tiles) % 8 == 0.
// R4: XCD-chunked bijective swizzle + small-tile-dim-fastest enumeration so
// consecutive blocks on one XCD reuse the large operand tile in its L2.
template<typename TO>
__global__ __launch_bounds__(256) void k_gemm_mfma(
    const f16* __restrict__ A, const f16* __restrict__ B,
    TO* __restrict__ CL, TO* __restrict__ CR, int K, int ldc, int split)
{
    __shared__ f16 As[128 * 64];
    __shared__ f16 Bs[128 * 64];
    int t = threadIdx.x;
    int w = t >> 6, lane = t & 63;
    int wm = w >> 1, wn = w & 1;

    int gx = gridDim.x, gy = gridDim.y;          // (m_tiles, n_tiles)
    int nwg = gx * gy;
    int orig = blockIdx.y * gx + blockIdx.x;     // dispatch order (x fastest)
    int swz = (orig & 7) * (nwg >> 3) + (orig >> 3);   // chunked XCD swizzle
    int mt, nt;
    if (gx <= gy) { mt = swz % gx; nt = swz / gx; }    // share B-tile
    else          { nt = swz % gy; mt = swz / gy; }    // share A-tile
    long m0 = (long)mt * 128;
    int n0 = nt * 128;

    f32x4 acc[4][4] = {};

    const f16* ga = A + (m0 + w * 8 + (lane >> 3)) * K + (lane & 7) * 8;
    const f16* gb = B + ((long)n0 + w * 8 + (lane >> 3)) * K + (lane & 7) * 8;
    f16* la = As + (w * 8) * 64;
    f16* lb = Bs + (w * 8) * 64;

    for (int kk = 0; kk < K; kk += 64) {
#pragma unroll
        for (int i = 0; i < 4; i++) {
            gload_lds16(ga + (long)i * 32 * K + kk, la + i * 32 * 64);
            gload_lds16(gb + (long)i * 32 * K + kk, lb + i * 32 * 64);
        }
        __syncthreads();

        const f16* pa = As + (wm * 64 + (lane & 15)) * 64 + (lane >> 4) * 8;
        const f16* pb = Bs + (wn * 64 + (lane & 15)) * 64 + (lane >> 4) * 8;
#pragma unroll
        for (int kb = 0; kb < 2; kb++) {
            f16x8 af[4], bf[4];
#pragma unroll
            for (int r = 0; r < 4; r++)
                af[r] = *(const f16x8*)(pa + r * 16 * 64 + kb * 32);
#pragma unroll
            for (int cn = 0; cn < 4; cn++)
                bf[cn] = *(const f16x8*)(pb + cn * 16 * 64 + kb * 32);
#pragma unroll
            for (int r = 0; r < 4; r++)
#pragma unroll
                for (int cn = 0; cn < 4; cn++)
                    acc[r][cn] = __builtin_amdgcn_mfma_f32_16x16x32_f16(
                        af[r], bf[cn], acc[r][cn], 0, 0, 0);
        }
        __syncthreads();
    }

    int rb = (lane >> 4) * 4;
    int cb = lane & 15;
#pragma unroll
    for (int r = 0; r < 4; r++) {
        long mrow = m0 + wm * 64 + r * 16 + rb;
#pragma unroll
        for (int reg = 0; reg < 4; reg++) {
            long row = mrow + reg;
            TO* Cp = (row < split) ? CL + row * ldc : CR + (row - split) * ldc;
#pragma unroll
            for (int cn = 0; cn < 4; cn++)
                Cp[n0 + wn * 64 + cn * 16 + cb] = (TO)acc[r][cn][reg];
        }
    }
}

// ---------------- dt: fp32 dot of F16 row with W rows 1152..1155, softplus --
__global__ __launch_bounds__(256) void k_dt(
    const f16* __restrict__ F, const float* __restrict__ W,
    const float* __restrict__ dt_bias, float* __restrict__ dtbuf)
{
    int t = threadIdx.x;
    int wv = t >> 6, lane = t & 63;
    long m = (long)blockIdx.x * 4 + wv;     // 0..65535
    f16x4 fv = *(const f16x4*)(F + m * 256 + lane * 4);
    float dots[4];
#pragma unroll
    for (int h = 0; h < 4; h++) {
        float4 w4 = *(const float4*)(W + (long)(1152 + h) * 256 + lane * 4);
        float d = (float)fv[0] * w4.x + (float)fv[1] * w4.y
                + (float)fv[2] * w4.z + (float)fv[3] * w4.w;
#pragma unroll
        for (int off = 32; off; off >>= 1) d += __shfl_down(d, off, 64);
        dots[h] = d;
    }
    if (lane == 0) {
        long sb = m >> 13;                  // side*4 + b
        long l = m & 8191;
#pragma unroll
        for (int h = 0; h < 4; h++) {
            float v = dots[h] + dt_bias[h];
            float sp = (v > 20.0f) ? v : log1pf(expf(v));
            dtbuf[(sb * 4 + h) * 8192 + l] = sp;
        }
    }
}

// ---------------- per-chunk cumsum of dt*A, and w = dt*exp(cumL-cum) --------
// R4: wave-parallel. One wave per (sb,h,c) group of 128 elements; lane holds
// 2 elems (float2), 6-step shuffle inclusive scan, fused w computation.
__global__ __launch_bounds__(256) void k_cum(
    const float* __restrict__ dtbuf, const float* __restrict__ A_log,
    float* __restrict__ cumbuf, float* __restrict__ wbuf)
{
    int wv = threadIdx.x >> 6, lane = threadIdx.x & 63;
    int g = blockIdx.x * 4 + wv;                // 2048 = sb(8)*h(4)*c(64)
    int c = g & 63, h = (g >> 6) & 3, sb = g >> 8;
    float A = -__expf(A_log[h]);
    long base = ((long)sb * 4 + h) * 8192 + c * 128;
    float2 d = *(const float2*)(dtbuf + base + lane * 2);
    float a0 = d.x * A;
    float p = a0 + d.y * A;                     // in-lane pair sum
    float s = p;
#pragma unroll
    for (int off = 1; off < 64; off <<= 1) {
        float v = __shfl_up(s, off, 64);
        if (lane >= off) s += v;
    }
    float excl = s - p;
    float c0 = excl + a0, c1 = excl + p;
    float cl = __shfl(s, 63, 64);               // chunk total
    *(float2*)(cumbuf + base + lane * 2) = make_float2(c0, c1);
    *(float2*)(wbuf + base + lane * 2) =
        make_float2(d.x * __expf(cl - c0), d.y * __expf(cl - c1));
}

// ---------------- causal conv1d on transposed x (contiguous along L) --------
__global__ __launch_bounds__(256) void k_conv_x(
    const f16* __restrict__ xT, const float* __restrict__ cw,
    const float* __restrict__ cb, f16* __restrict__ XCt)
{
    int bid = blockIdx.x;               // c(512) | b(4) | tile(4)
    int c = bid >> 4;
    int b = (bid >> 2) & 3;
    int tile = bid & 3;
    int l0 = tile * 2048 + threadIdx.x * 8;
    const f16* row = xT + (long)c * 65536 + b * 8192;   // left cols only
    float w0 = cw[c * 4 + 0], w1 = cw[c * 4 + 1],
          w2 = cw[c * 4 + 2], w3 = cw[c * 4 + 3];
    float bv = cb[c];
    float xv[11];
    f16x8 v = *(const f16x8*)(row + l0);
#pragma unroll
    for (int q = 0; q < 8; q++) xv[3 + q] = (float)v[q];
    if (l0 > 0) {
        xv[0] = (float)row[l0 - 3];
        xv[1] = (float)row[l0 - 2];
        xv[2] = (float)row[l0 - 1];
    } else { xv[0] = xv[1] = xv[2] = 0.f; }
    f16x8 o;
#pragma unroll
    for (int q = 0; q < 8; q++) {
        float acc = bv + w0 * xv[q] + w1 * xv[q + 1] + w2 * xv[q + 2] + w3 * xv[q + 3];
        o[q] = (f16)siluf(acc);
    }
    *(f16x8*)(XCt + (long)c * 32768 + b * 8192 + l0) = o;
}

// ---------------- causal conv1d on left B/C (row-major [l][128]) ------------
__global__ __launch_bounds__(256) void k_conv_bc(
    const f16* __restrict__ bcLr, const float* __restrict__ cw,
    const float* __restrict__ cb, f16* __restrict__ bcL)
{
    long idx = (long)blockIdx.x * 256 + threadIdx.x;    // 32768*128
    int n = (int)(idx & 127);
    long m = idx >> 7;
    int l = (int)(m & 8191);
    float acc = cb[512 + n];
#pragma unroll
    for (int k = 0; k < 4; k++) {
        int j = l - 3 + k;
        if (j >= 0) acc += cw[(512 + n) * 4 + k] * (float)bcLr[(m - 3 + k) * 128 + n];
    }
    bcL[m * 128 + n] = (f16)siluf(acc);
}

// ---------------- SSD phase A: MFMA chunked formulation (R8: 48KB LDS) ------
// LDS 48 KB: Xs[p=128][j=128] (32KB) | Bs[j=128][n=64] (16KB); Ms[i=128]
// [jl=64] overlays Bs after G. 3 blocks/CU (vs 2 at 64KB).
// Tiles XOR-swizzled in 16B chunks: phys_chunk = log_chunk ^ (row & 7).
// C is NOT staged: G-phase A-operand reads C fragments from global (L2/L3-
// resident; k_ssd_c-proven pattern). M precomputed into packed f16 regs
// (mv[8]) so g[4][4] dies before y[4][4] allocates; Y = M.X runs as two
// K=64 j-halves: wn==half waves dump their mv to Ms, barrier, all MFMA.
__global__ __launch_bounds__(256) void k_ssd_a(
    const f16* __restrict__ xT, const f16* __restrict__ XCt,
    const f16* __restrict__ bcR, const f16* __restrict__ bcL,
    const float* __restrict__ dtbuf, const float* __restrict__ cumbuf,
    const float* __restrict__ wbuf, const float* __restrict__ Dvec,
    f16* __restrict__ ybuf, f16* __restrict__ states)
{
    extern __shared__ f16 sm[];
    f16* Xs = sm;            // [p][j]   swizzled, 32KB
    f16* Bs = sm + 16384;    // [j][n]   swizzled, 16KB
    f16* Ms = sm + 16384;    // [i][jl]  overlay after G, 16KB

    int t = threadIdx.x;
    int w = t >> 6, lane = t & 63;
    int quad = lane >> 4, l16 = lane & 15;
    int wm = w >> 1, wn = w & 1;
    int bid = blockIdx.x;
    int side = bid >> 10, rem = bid & 1023;
    int b = rem >> 8, c = (rem >> 2) & 63, h = rem & 3;
    long l0 = (long)b * 8192 + c * 128;
    long dtbase = ((long)(side * 4 + b) * 4 + h) * 8192 + c * 128;

    const f16* Xg; long ldx;
    const f16 *Bg, *Cg;
    if (side == 0) {
        Xg = xT + (long)(h * 128) * 65536 + 32768 + l0; ldx = 65536;
        Bg = bcR + l0 * 128;
        Cg = bcL + l0 * 128 + 64;
    } else {
        Xg = XCt + (long)(h * 128) * 32768 + l0;        ldx = 32768;
        Bg = bcL + l0 * 128;
        Cg = bcR + l0 * 128 + 64;
    }

    int sw8 = l16 & 7;   // row&7 for all MFMA-phase fragment rows (row%16==l16)

    // stage X (4 rows/call): lane (quad,l16) lands at LDS (row r0+quad, chunk
    // l16) -> source column chunk = l16 ^ (row&7)
#pragma unroll
    for (int q = 0; q < 8; q++) {
        int r0 = w * 32 + q * 4;
        int R = r0 + quad;
        gload_lds16(Xg + (long)R * ldx + ((l16 ^ (R & 7)) << 3), Xs + r0 * 128);
    }
    // stage B (8 rows/call): lane lands at (row r0+(lane>>3), chunk lane&7)
    // -> source chunk = (lane&7) ^ (row&7)
#pragma unroll
    for (int q = 0; q < 4; q++) {
        int r0 = w * 32 + q * 8;
        int R = r0 + (lane >> 3);
        int cc = ((lane & 7) ^ (R & 7)) << 3;
        gload_lds16(Bg + (long)R * 128 + cc, Bs + r0 * 64);
    }

    float cum_i[16], cum_j[4], dt_j[4];
#pragma unroll
    for (int r = 0; r < 4; r++)
#pragma unroll
        for (int reg = 0; reg < 4; reg++)
            cum_i[r * 4 + reg] = cumbuf[dtbase + wm * 64 + r * 16 + quad * 4 + reg];
#pragma unroll
    for (int cn = 0; cn < 4; cn++) {
        int j = wn * 64 + cn * 16 + l16;
        cum_j[cn] = cumbuf[dtbase + j];
        dt_j[cn] = dtbuf[dtbase + j];
    }
    float Dh = Dvec[h];
    __syncthreads();

    // G = C . B^T  (K=64): A-operand direct from global C
    f32x4 g[4][4] = {};
#pragma unroll
    for (int kb = 0; kb < 2; kb++) {
        f16x8 af[4], bf[4];
#pragma unroll
        for (int r = 0; r < 4; r++)
            af[r] = *(const f16x8*)(Cg + (long)(wm * 64 + r * 16 + l16) * 128
                                       + quad * 8 + kb * 32);
#pragma unroll
        for (int cn = 0; cn < 4; cn++)
            bf[cn] = *(const f16x8*)(Bs + (wn * 64 + cn * 16 + l16) * 64
                                        + (((quad + kb * 4) ^ sw8) << 3));
#pragma unroll
        for (int r = 0; r < 4; r++)
#pragma unroll
            for (int cn = 0; cn < 4; cn++)
                g[r][cn] = __builtin_amdgcn_mfma_f32_16x16x32_f16(
                    af[r], bf[cn], g[r][cn], 0, 0, 0);
    }

    // M precompute into packed f16 regs (g dies here; all thread's j in wn-half)
    f16x8 mv[8];
#pragma unroll
    for (int r = 0; r < 4; r++)
#pragma unroll
        for (int cn = 0; cn < 4; cn++)
#pragma unroll
            for (int reg = 0; reg < 4; reg++) {
                int i = wm * 64 + r * 16 + quad * 4 + reg;
                int j = wn * 64 + cn * 16 + l16;
                float v = 0.f;
                if (i >= j)
                    v = g[r][cn][reg] * fexpf(cum_i[r * 4 + reg] - cum_j[cn]) * dt_j[cn];
                if (i == j) v += Dh;
                mv[r * 2 + (cn >> 1)][(cn & 1) * 4 + reg] = (f16)v;
            }
    __syncthreads();   // all Bs reads done -> Ms may overlay

    // Y = M . X as two K=64 j-halves through the 16KB Ms overlay
    f32x4 y[4][4] = {};
#pragma unroll
    for (int half = 0; half < 2; half++) {
        if (wn == half) {
#pragma unroll
            for (int r = 0; r < 4; r++)
#pragma unroll
                for (int cn = 0; cn < 4; cn++)
#pragma unroll
                    for (int reg = 0; reg < 4; reg++) {
                        int i = wm * 64 + r * 16 + quad * 4 + reg;
                        int jl = cn * 16 + l16;
                        Ms[i * 64 + ((((jl >> 3) ^ (i & 7))) << 3) + (jl & 7)] =
                            mv[r * 2 + (cn >> 1)][(cn & 1) * 4 + reg];
                    }
        }
        __syncthreads();
#pragma unroll
        for (int kb = 0; kb < 2; kb++) {
            f16x8 af[4], bf[4];
#pragma unroll
            for (int r = 0; r < 4; r++)
                af[r] = *(const f16x8*)(Ms + (wm * 64 + r * 16 + l16) * 64
                                           + (((quad + kb * 4) ^ sw8) << 3));
#pragma unroll
            for (int cn = 0; cn < 4; cn++)
                bf[cn] = *(const f16x8*)(Xs + (wn * 64 + cn * 16 + l16) * 128
                                            + (((half * 8 + quad + kb * 4) ^ sw8) << 3));
#pragma unroll
            for (int r = 0; r < 4; r++)
#pragma unroll
                for (int cn = 0; cn < 4; cn++)
                    y[r][cn] = __builtin_amdgcn_mfma_f32_16x16x32_f16(
                        af[r], bf[cn], y[r][cn], 0, 0, 0);
        }
        if (half == 0) __syncthreads();   // Ms reads done before overwrite
    }

    long ybase = (long)side * 32768 + l0;
#pragma unroll
    for (int r = 0; r < 4; r++)
#pragma unroll
        for (int reg = 0; reg < 4; reg++) {
            int i = wm * 64 + r * 16 + quad * 4 + reg;
#pragma unroll
            for (int cn = 0; cn < 4; cn++) {
                int p = wn * 64 + cn * 16 + l16;
                ybuf[(ybase + i) * 512 + h * 128 + p] = (f16)y[r][cn][reg];
            }
        }

    // states = X^T(weighted B): A=Xs[p][j], B-frags built from global B * w_j
    f32x4 s[4][2] = {};
#pragma unroll
    for (int kb = 0; kb < 4; kb++) {
        float wj[8];
#pragma unroll
        for (int jj = 0; jj < 8; jj++)
            wj[jj] = wbuf[dtbase + kb * 32 + quad * 8 + jj];
        f16x8 af[4], bf[2];
#pragma unroll
        for (int r = 0; r < 4; r++)
            af[r] = *(const f16x8*)(Xs + (wm * 64 + r * 16 + l16) * 128
                                       + (((quad + kb * 4) ^ sw8) << 3));
#pragma unroll
        for (int cn = 0; cn < 2; cn++) {
            int n = wn * 32 + cn * 16 + l16;
#pragma unroll
            for (int jj = 0; jj < 8; jj++) {
                int j = kb * 32 + quad * 8 + jj;
                bf[cn][jj] = (f16)((float)Bg[(long)j * 128 + n] * wj[jj]);
            }
        }
#pragma unroll
        for (int r = 0; r < 4; r++)
#pragma unroll
            for (int cn = 0; cn < 2; cn++)
                s[r][cn] = __builtin_amdgcn_mfma_f32_16x16x32_f16(
                    af[r], bf[cn], s[r][cn], 0, 0, 0);
    }
    long sbase = (((long)(side * 4 + b) * 64 + c) * 4 + h) * 128;
#pragma unroll
    for (int r = 0; r < 4; r++)
#pragma unroll
        for (int reg = 0; reg < 4; reg++) {
            int p = wm * 64 + r * 16 + quad * 4 + reg;
#pragma unroll
            for (int cn = 0; cn < 2; cn++) {
                int n = wn * 32 + cn * 16 + l16;
                states[(sbase + p) * 64 + n] = (f16)s[r][cn][reg];
            }
        }
}

// ---------------- inter-chunk scan over 64 chunks (in place, fp16) ----------
// R5: load all 64 chunk-values into regs first (independent loads pipeline
// under vmcnt) instead of a 64-deep dependent load->store chain.
__global__ __launch_bounds__(256) void k_scan(
    f16* __restrict__ states, const float* __restrict__ cumbuf)
{
    long g = (long)blockIdx.x * 256 + threadIdx.x;   // 262144 threads
    int n = (int)(g & 63);
    int p = (int)((g >> 6) & 127);
    int h = (int)((g >> 13) & 3);
    int sb = (int)(g >> 15);                         // side*4+b
    long sbase = (((long)sb * 256 + h) * 128 + p) * 64 + n;   // c=0
    long cbase = ((long)sb * 4 + h) * 8192 + 127;
    float sv[64];
#pragma unroll
    for (int c = 0; c < 64; c++)
        sv[c] = (float)states[sbase + (long)c * 32768];
    float hr = 0.f;
#pragma unroll
    for (int c = 0; c < 64; c++) {
        states[sbase + (long)c * 32768] = (f16)hr;   // hprev for chunk c
        hr = hr * fexpf(cumbuf[cbase + (long)c * 128]) + sv[c];
    }
}

// ---------------- fused SSD phase C + gated rmsnorm (v3) --------------------
// Per block: (side,b,chunk,quarter) = 32 rows x 512 cols. 256 threads, 4
// waves, 32KB LDS -> 4 blocks/CU (vs 2 at 64KB in v2).
// Work id XCD-chunk-swizzled so the 4 quarter-blocks of one (sb,c) stay on
// one XCD and the shared 64KB states tile hits its L2.
// LDS: cS f16 [32 rows][64 chunks of 16B], phys_chunk = chunk ^ (row&7).
// P1: wave w = head w: corr = exp(cum_i) * C(32x64).hprev^T(128x64) [MFMA,
//     acc[2][8]] -> plain swizzled writes into cS cols h*128..h*128+127.
// P2a: 8 threads/row: g = (y + corr)*silu(z); ssq over 8 lanes (3 shfl_xor);
//     write g back to own cS slots (no reg arrays -> no spills).
// P2b: scale by rsqrt(mean+eps)*nw, store ybuf.
__global__ __launch_bounds__(256) void k_ssd_cn(
    const f16* __restrict__ bcR, const f16* __restrict__ bcL,
    const f16* __restrict__ states, const float* __restrict__ cumbuf,
    const f16* __restrict__ zbuf, const float* __restrict__ nw,
    f16* __restrict__ ybuf)
{
    extern __shared__ f16 cS[];   // [32][512] swizzled
    int t = threadIdx.x;
    int w = t >> 6, lane = t & 63;
    int quad = lane >> 4, l16 = lane & 15;
    int bid = blockIdx.x;                     // 2048 blocks
    int work = (bid & 7) * 256 + (bid >> 3);  // XCD-chunked bijective swizzle
    int sb = work >> 8, rem = work & 255;     // sb(8) | c(64) | quarter(4)
    int c = rem >> 2, quarter = rem & 3;
    int side = sb >> 2, b = sb & 3;
    long lrow0 = (long)b * 8192 + c * 128 + quarter * 32;  // row in side bufs
    long grow0 = (long)side * 32768 + lrow0;               // row in ybuf/zbuf

    // ---- P1: wave w computes head w's correction (32 rows x 128 cols) ----
    const f16* Cg = ((side == 0) ? bcL : bcR) + lrow0 * 128 + 64;
    int h = w;
    long stile = (((long)sb * 64 + c) * 4 + h) * 8192;
    long dtb = ((long)sb * 4 + h) * 8192 + c * 128 + quarter * 32;
    f16x8 af[2][2];
#pragma unroll
    for (int r = 0; r < 2; r++)
#pragma unroll
        for (int kb = 0; kb < 2; kb++)
            af[r][kb] = *(const f16x8*)(Cg + (long)(r * 16 + l16) * 128
                                           + quad * 8 + kb * 32);
    f32x4 acc[2][8] = {};
#pragma unroll
    for (int kb = 0; kb < 2; kb++) {
        f16x8 bf[8];
#pragma unroll
        for (int cn = 0; cn < 8; cn++)
            bf[cn] = *(const f16x8*)(states + stile
                        + (long)(cn * 16 + l16) * 64 + quad * 8 + kb * 32);
#pragma unroll
        for (int r = 0; r < 2; r++)
#pragma unroll
            for (int cn = 0; cn < 8; cn++)
                acc[r][cn] = __builtin_amdgcn_mfma_f32_16x16x32_f16(
                    af[r][kb], bf[cn], acc[r][cn], 0, 0, 0);
    }
#pragma unroll
    for (int r = 0; r < 2; r++)
#pragma unroll
        for (int reg = 0; reg < 4; reg++) {
            int i = r * 16 + quad * 4 + reg;
            float ex = fexpf(cumbuf[dtb + i]);
#pragma unroll
            for (int cn = 0; cn < 8; cn++) {
                int col = h * 128 + cn * 16 + l16;
                int addr = i * 512 + (((col >> 3) ^ (i & 7)) << 3) + (col & 7);
                cS[addr] = (f16)(ex * acc[r][cn][reg]);
            }
        }
    __syncthreads();

    // ---- P2a: g = (y + corr) * silu(z); ssq; write g to own slots ----
    int row = t >> 3, q8 = t & 7;     // 8 threads/row, 32 rows
    int rs = row & 7;
    long grow = grow0 + row;
    const f16* yrow = ybuf + grow * 512;
    const f16* zrow = zbuf + grow * 512;
    float ssq = 0.f;
#pragma unroll
    for (int k = 0; k < 8; k++) {
        int lg = k * 8 + q8;
        f16* slot = cS + row * 512 + ((lg ^ rs) << 3);
        f16x8 cv = *(const f16x8*)slot;
        f16x8 yv = *(const f16x8*)(yrow + lg * 8);
        f16x8 zv = *(const f16x8*)(zrow + lg * 8);
        f16x8 gg;
#pragma unroll
        for (int qq = 0; qq < 8; qq++) {
            float gf = ((float)yv[qq] + (float)cv[qq]) * siluf((float)zv[qq]);
            gg[qq] = (f16)gf;
            ssq += gf * gf;
        }
        *(f16x8*)slot = gg;
    }
    ssq += __shfl_xor(ssq, 1, 64);
    ssq += __shfl_xor(ssq, 2, 64);
    ssq += __shfl_xor(ssq, 4, 64);
    float sc = rsqrtf(ssq * (1.0f / 512.0f) + 1e-5f);

    // ---- P2b: scale by sc*nw, write ybuf (same-thread slots, no barrier) ----
    f16* orow = ybuf + grow * 512;
#pragma unroll
    for (int k = 0; k < 8; k++) {
        int lg = k * 8 + q8;
        f16x8 gg = *(const f16x8*)(cS + row * 512 + ((lg ^ rs) << 3));
        float4 w0 = *(const float4*)(nw + lg * 8);
        float4 w1 = *(const float4*)(nw + lg * 8 + 4);
        f16x8 o;
        o[0] = (f16)((float)gg[0] * sc * w0.x);
        o[1] = (f16)((float)gg[1] * sc * w0.y);
        o[2] = (f16)((float)gg[2] * sc * w0.z);
        o[3] = (f16)((float)gg[3] * sc * w0.w);
        o[4] = (f16)((float)gg[4] * sc * w1.x);
        o[5] = (f16)((float)gg[5] * sc * w1.y);
        o[6] = (f16)((float)gg[6] * sc * w1.z);
        o[7] = (f16)((float)gg[7] * sc * w1.w);
        *(f16x8*)(orow + lg * 8) = o;
    }
}

// ---------------------------------------------------------------------------
extern "C" void kernel_launch(void* const* d_in, const int* in_sizes, int n_in,
                              void* d_out, int out_size, void* d_ws, size_t ws_size,
                              hipStream_t stream)
{
    (void)in_sizes; (void)n_in; (void)out_size; (void)ws_size;
    const float* limg = (const float*)d_in[0];
    const float* rimg = (const float*)d_in[1];
    const float* dsw  = (const float*)d_in[2];
    const float* dsb  = (const float*)d_in[3];
    const float* ipw  = (const float*)d_in[4];
    const float* cw   = (const float*)d_in[5];
    const float* cb   = (const float*)d_in[6];
    const float* dtb  = (const float*)d_in[7];
    const float* alog = (const float*)d_in[8];
    const float* Dv   = (const float*)d_in[9];
    const float* nw   = (const float*)d_in[10];
    const float* opw  = (const float*)d_in[11];
    float* out = (float*)d_out;

    char* ws = (char*)d_ws;
    f16*   F16    = (f16*)  (ws + 0);
    f16*   ipw16  = (f16*)  (ws + 33554432);
    f16*   opw16  = (f16*)  (ws + 34146304);
    float* dtbuf  = (float*)(ws + 34408448);
    float* cumbuf = (float*)(ws + 35457024);
    float* wbuf   = (float*)(ws + 36505600);
    f16*   xT     = (f16*)  (ws + 37554176);
    f16*   XCt    = (f16*)  (ws + 104663040);
    f16*   bcLr   = (f16*)  (ws + 138217472);
    f16*   bcR    = (f16*)  (ws + 146606080);
    f16*   bcL    = (f16*)  (ws + 154994688);
    f16*   ybuf   = (f16*)  (ws + 163383296);
    f16*   states = (f16*)  (ws + 230492160);
    f16*   zbuf   = xT;                          // alias (xT dead after ssd_a)

    const int BIG = 1 << 30;
    k_downsample<<<4096, 256, 0, stream>>>(limg, rimg, dsw, dsb, F16);
    k_cvt<<<1156, 256, 0, stream>>>(ipw, ipw16, 1156 * 256);
    k_cvt<<<512, 256, 0, stream>>>(opw, opw16, 256 * 512);
    // B/C columns (weights rows 1024..1151): out [l][128], split L/R
    k_gemm_mfma<f16><<<dim3(512, 1), 256, 0, stream>>>(
        F16, ipw16 + 1024 * 256, bcLr, bcR, 256, 128, 32768);
    // x columns TRANSPOSED: A=weights rows 512..1023, B=F16 -> xT[512][65536]
    k_gemm_mfma<f16><<<dim3(4, 512), 256, 0, stream>>>(
        ipw16 + 512 * 256, F16, xT, xT, 256, 65536, BIG);
    k_dt<<<16384, 256, 0, stream>>>(F16, ipw, dtb, dtbuf);
    k_cum<<<512, 256, 0, stream>>>(dtbuf, alog, cumbuf, wbuf);
    k_conv_x<<<8192, 256, 0, stream>>>(xT, cw, cb, XCt);
    k_conv_bc<<<16384, 256, 0, stream>>>(bcLr, cw, cb, bcL);
    k_ssd_a<<<2048, 256, 49152, stream>>>(
        xT, XCt, bcR, bcL, dtbuf, cumbuf, wbuf, Dv, ybuf, states);
    k_scan<<<1024, 256, 0, stream>>>(states, cumbuf);
    // z = F @ ipw[0:512]^T (into region freed by xT) -- before fused epilogue
    k_gemm_mfma<f16><<<dim3(512, 4), 256, 0, stream>>>(
        F16, ipw16, zbuf, zbuf, 256, 512, BIG);
    // fused: y += exp(cum)*C.hprev^T ; y = rmsnorm(y*silu(z))*nw
    k_ssd_cn<<<2048, 256, 32768, stream>>>(
        bcR, bcL, states, cumbuf, zbuf, nw, ybuf);
    // out = y @ opw^T (fp32 out), split L/R halves of d_out
    k_gemm_mfma<float><<<dim3(512, 2), 256, 0, stream>>>(
        ybuf, opw16, out, out + (long)32768 * 256, 512, 256, 32768);
}